// Round 11
// baseline (627.736 us; speedup 1.0000x reference)
//
#include <hip/hip_runtime.h>
#include <stdint.h>

// Problem constants
#define B_   2
#define T_   4096
#define C_   768
#define H_   12
#define D_   64
#define BH_  24      // B_*H_
#define M_   8192    // B_*T_
#define K_   768
#define N1_  2304    // 3*C_

#define NEG_BIG (-1.0e30f)
// Q pre-scale: (1/sqrt(D)) * log2(e) -> attention runs in exp2 domain
#define QSCALE 0.18033688011112042f

typedef short bf16x8 __attribute__((ext_vector_type(8)));
typedef float f32x4  __attribute__((ext_vector_type(4)));
typedef float f32x16 __attribute__((ext_vector_type(16)));
typedef uint32_t u32x4 __attribute__((ext_vector_type(4)));
typedef int i32x2 __attribute__((ext_vector_type(2)));

typedef const __attribute__((address_space(1))) void* as1cv;
typedef __attribute__((address_space(3))) void*       as3v;

__device__ __forceinline__ void gload_lds16(const void* g, void* l) {
  __builtin_amdgcn_global_load_lds((as1cv)g, (as3v)l, 16, 0, 0);
}

// fp32 -> bf16 bits, round-to-nearest-even (input-fidelity paths).
// NOTE: v_cvt_pk_bf16_f32 inline-asm is POISONED on this toolchain (R2: NaN,
// R6: absmax 7.4e30). Software paths only.
__device__ __forceinline__ unsigned short f2bf(float f) {
  uint32_t x = __builtin_bit_cast(uint32_t, f);
  uint32_t r = (x + 0x7fffu + ((x >> 16) & 1u)) >> 16;
  return (unsigned short)r;
}

// cheap scalar pack: round-half-up, 2 VALU ops (<=0.5 ulp; 4x absmax headroom)
__device__ __forceinline__ unsigned short f2bf_hu(float f) {
  return (unsigned short)((__builtin_bit_cast(uint32_t, f) + 0x8000u) >> 16);
}

// cheap pair pack: round-half-up + byte-select (3 VALU via v_perm_b32)
#if __has_builtin(__builtin_amdgcn_perm)
__device__ __forceinline__ uint32_t pack_hu(float lo, float hi) {
  uint32_t a = __builtin_bit_cast(uint32_t, lo) + 0x8000u;
  uint32_t b = __builtin_bit_cast(uint32_t, hi) + 0x8000u;
  return __builtin_amdgcn_perm(b, a, 0x07060302u);
}
#else
__device__ __forceinline__ uint32_t pack_hu(float lo, float hi) {
  uint32_t a = __builtin_bit_cast(uint32_t, lo) + 0x8000u;
  uint32_t b = __builtin_bit_cast(uint32_t, hi) + 0x8000u;
  return (b & 0xFFFF0000u) | (a >> 16);
}
#endif

#if __has_builtin(__builtin_amdgcn_permlane32_swap)
#define HAVE_PLSWAP 1
#else
#define HAVE_PLSWAP 0
#endif

// native 2^x (v_exp_f32)
#if __has_builtin(__builtin_amdgcn_exp2f)
__device__ __forceinline__ float fast_exp2(float x) { return __builtin_amdgcn_exp2f(x); }
#else
__device__ __forceinline__ float fast_exp2(float x) { return __expf(x * 0.69314718056f); }
#endif

// ---------------------------------------------------------------- cast x -> bf16
__global__ void cast_kernel(const float* __restrict__ in, unsigned short* __restrict__ out, int n4) {
  int idx = blockIdx.x * blockDim.x + threadIdx.x;
  int stride = gridDim.x * blockDim.x;
  for (int i = idx; i < n4; i += stride) {
    float4 v = reinterpret_cast<const float4*>(in)[i];
    ushort4 o;
    o.x = f2bf(v.x); o.y = f2bf(v.y); o.z = f2bf(v.z); o.w = f2bf(v.w);
    reinterpret_cast<ushort4*>(out)[i] = o;
  }
}

// ------------------------------------------- transpose + cast: in[K][N] -> out[N][K] bf16
__global__ void transpose_cast(const float* __restrict__ in, unsigned short* __restrict__ out,
                               int K, int N) {
  __shared__ float tile[32][33];
  const int tx = threadIdx.x, ty = threadIdx.y;
  const int n = blockIdx.x * 32 + tx;
  #pragma unroll
  for (int r = 0; r < 4; ++r) {
    int k = blockIdx.y * 32 + ty + r * 8;
    tile[ty + r * 8][tx] = in[(size_t)k * N + n];
  }
  __syncthreads();
  const int k = blockIdx.y * 32 + tx;
  #pragma unroll
  for (int r = 0; r < 4; ++r) {
    int nn = blockIdx.x * 32 + ty + r * 8;
    out[(size_t)nn * K + k] = f2bf(tile[tx][ty + r * 8]);
  }
}

// ---------------------------------------------------------------- GEMM (m97-like)
// C[M][N] = A[M][768] * BT[N][768]^T + bias
// MODE 0: scatter epilogue -> Q [BH][T][D] (xQSCALE, exp2 domain), K & V^T in
//         MFMA-tiled layouts (attn fragment loads = base + lane*16B bursts).
// MODE 1: plain fp32 store to fo[M][768]
template <int MODE>
__global__ __launch_bounds__(256) void gemm_kernel(
    const unsigned short* __restrict__ A, const unsigned short* __restrict__ BT,
    const float* __restrict__ bias,
    unsigned short* __restrict__ o0, unsigned short* __restrict__ o1,
    unsigned short* __restrict__ o2, float* __restrict__ fo) {
  __shared__ __align__(16) unsigned short Al[128 * 32];
  __shared__ __align__(16) unsigned short Bl[128 * 32];
  const int tid = threadIdx.x;
  const int w = tid >> 6, lane = tid & 63;
  const int g = lane >> 4, c16 = lane & 15;
  const int wr = w >> 1, wc = w & 1;
  const int m0 = blockIdx.x * 128, n0 = blockIdx.y * 128;

  f32x4 acc[4][4] = {};

  for (int k0 = 0; k0 < K_; k0 += 32) {
    __syncthreads();
    #pragma unroll
    for (int q = 0; q < 2; ++q) {
      const int ch = (w * 2 + q) * 64 + lane;     // 0..511
      const int row = ch >> 2, kb = ch & 3;       // 128 rows x 4 x 16B
      gload_lds16(A  + (size_t)(m0 + row) * K_ + k0 + kb * 8, &Al[(w * 2 + q) * 512]);
      gload_lds16(BT + (size_t)(n0 + row) * K_ + k0 + kb * 8, &Bl[(w * 2 + q) * 512]);
    }
    __syncthreads();
    bf16x8 af[4], bfr[4];
    #pragma unroll
    for (int i = 0; i < 4; ++i) {
      af[i]  = *reinterpret_cast<const bf16x8*>(&Al[(wr * 64 + i * 16 + c16) * 32 + g * 8]);
      bfr[i] = *reinterpret_cast<const bf16x8*>(&Bl[(wc * 64 + i * 16 + c16) * 32 + g * 8]);
    }
    #pragma unroll
    for (int i = 0; i < 4; ++i)
      #pragma unroll
      for (int j = 0; j < 4; ++j)
        acc[i][j] = __builtin_amdgcn_mfma_f32_16x16x32_bf16(af[i], bfr[j], acc[i][j], 0, 0, 0);
  }

  const int which = (MODE == 0) ? (n0 / 768) : 0;
  #pragma unroll
  for (int i = 0; i < 4; ++i) {
    const int mbase = m0 + wr * 64 + i * 16 + g * 4;
    #pragma unroll
    for (int j2 = 0; j2 < 4; ++j2) {
      const int n = n0 + wc * 64 + j2 * 16 + c16;
      const float bv = bias[n];
      #pragma unroll
      for (int j = 0; j < 4; ++j) {
        float v = acc[i][j2][j] + bv;
        const int mm = mbase + j;
        if constexpr (MODE == 0) {
          const int cc = n - which * 768;
          const int hh = cc >> 6, dd = cc & 63;
          const int bb = mm >> 12, tt = mm & 4095;   // tt = kv/time index
          const size_t bh = (size_t)bb * H_ + hh;
          const size_t hb = bh * T_ * D_;
          if (which == 0) {
            o0[hb + (size_t)tt * D_ + dd] = f2bf_hu(v * QSCALE);  // Q, exp2 domain
          } else if (which == 1) {
            // K tiled: kv=tt, k=dd
            const int addr = ((tt >> 5) * 4 + (dd >> 4)) * 512 +
                             ((tt & 31) + ((dd >> 3) & 1) * 32) * 8 + (dd & 7);
            o1[hb + addr] = f2bf_hu(v);
          } else {
            // V^T tiled: d=dd, kv=tt
            const int addr = (tt >> 6) * 4096 + (dd >> 5) * 2048 +
                             ((tt >> 4) & 3) * 512 +
                             ((dd & 31) + ((tt >> 3) & 1) * 32) * 8 + (tt & 7);
            o2[hb + addr] = f2bf_hu(v);
          }
        } else {
          fo[(size_t)mm * 768 + n] = v;
        }
      }
    }
  }
}

// ---------------------------------------------------------------- flash attention
// 4 waves per block, SAME 32 q-rows, kv tiles split round-robin (wave w takes
// tiles it ≡ w mod 4) — quarters the serial causal tail (64 -> 16 tiles) and
// quadruples resident waves. Private online-softmax state per wave; waves 1-3
// publish (m,l,y) via LDS once; wave0 merges lane-elementwise and stores.
// Tiled K/V layouts: every fragment load is base + lane*16B (coalesced burst).
// Depth-2 K register pipeline per wave. Swapped QK^T: lane owns ONE q-row.
// exp2 domain (Q pre-scaled by log2e/8): bare v_exp_f32, no muls.
__global__ __launch_bounds__(256, 4) void attn_kernel(
    const unsigned short* __restrict__ Qb, const unsigned short* __restrict__ Kb,
    const unsigned short* __restrict__ Vt, unsigned short* __restrict__ Yb) {
  __shared__ float Ml[3][64];
  __shared__ float Ll[3][64];
  __shared__ __align__(16) float Yl[3][32][64];  // [partial][reg][lane] — conflict-free

  const int tidx = threadIdx.x;
  const int wv = tidx >> 6;       // 0..3: kv-split partner index
  const int lane = tidx & 63;
  const int q31 = lane & 31, hi = lane >> 5;
  const int bid = blockIdx.x;
  const int bh = bid % BH_;                     // bid%8 == bh%8 -> bh->XCD locality
  const int strip = (T_ / 32 - 1) - bid / BH_;  // 127..0, longest first
  const int q0 = strip * 32;
  const int qg = q0 + q31;  // this lane's q row

  const int bb = bh / H_, hh = bh % H_;
  const size_t hoff = (size_t)bh * T_ * D_;
  const unsigned short* Qh = Qb + hoff;
  const unsigned short* Kh = Kb + hoff + lane * 8;  // tiled: all frag loads + lane*8
  const unsigned short* Vh = Vt + hoff + lane * 8;

  // Q fragments: B-operand, col = q31, k = s*16 + hi*8 + e (one-time gather)
  bf16x8 qf[4];
  #pragma unroll
  for (int s = 0; s < 4; ++s)
    qf[s] = *reinterpret_cast<const bf16x8*>(&Qh[(size_t)qg * D_ + s * 16 + hi * 8]);

  float mrun = NEG_BIG, lrun = 0.f;
  f32x16 y0 = {}, y1 = {};

  const int nt = ((q0 + 31) >> 6) + 1;  // kv tiles 0..floor((q0+31)/64)

  // K fragment double buffer; tiled addr: it*4096 + (s>>2)*2048 + (s&3)*512
  bf16x8 kfA[8], kfB[8];

  auto tile_step = [&](bf16x8 (&kfc)[8], bf16x8 (&kfn)[8], int it) {
    const int kv0 = it << 6;

    // ---- V fragments for current tile (tiled: it*4096 + half*2048 + ks*512)
    const unsigned short* vB = Vh + it * 4096;
    bf16x8 vfA[4], vfB[4];
    #pragma unroll
    for (int ks = 0; ks < 4; ++ks) {
      vfA[ks] = *reinterpret_cast<const bf16x8*>(vB + ks * 512);
      vfB[ks] = *reinterpret_cast<const bf16x8*>(vB + 2048 + ks * 512);
    }

    // ---- K prefetch for MY next tile, it+4 (tail over-read stays in ws)
    const unsigned short* kN = Kh + it * 4096 + 16384;
    #pragma unroll
    for (int s = 0; s < 8; ++s)
      kfn[s] = *reinterpret_cast<const bf16x8*>(kN + (s >> 2) * 2048 + (s & 3) * 512);

    // ---- S^T = K * Q^T : two 32x32 half-tiles (kv 0..31, 32..63)
    f32x16 s0 = {}, s1 = {};
    #pragma unroll
    for (int s = 0; s < 4; ++s)
      s0 = __builtin_amdgcn_mfma_f32_32x32x16_bf16(kfc[s], qf[s], s0, 0, 0, 0);
    #pragma unroll
    for (int s = 0; s < 4; ++s)
      s1 = __builtin_amdgcn_mfma_f32_32x32x16_bf16(kfc[4 + s], qf[s], s1, 0, 0, 0);

    // ---- causal mask (finite sentinel); kv_local = (r&3)+8*(r>>2)+4*hi
    if (kv0 + 63 > q0) {
      #pragma unroll
      for (int r = 0; r < 16; ++r) {
        const int kvl = (r & 3) + 8 * (r >> 2) + 4 * hi;
        s0[r] = (kv0 + kvl > qg)      ? NEG_BIG : s0[r];
        s1[r] = (kv0 + 32 + kvl > qg) ? NEG_BIG : s1[r];
      }
    }

    // ---- column max: in-lane tree + cross-half merge (shfl_xor 32)
    float a[16];
    #pragma unroll
    for (int r = 0; r < 8; ++r) a[r] = fmaxf(s0[2 * r], s0[2 * r + 1]);
    #pragma unroll
    for (int r = 0; r < 8; ++r) a[8 + r] = fmaxf(s1[2 * r], s1[2 * r + 1]);
    #pragma unroll
    for (int st = 8; st > 0; st >>= 1)
      #pragma unroll
      for (int r = 0; r < 16; ++r) if (r < st) a[r] = fmaxf(a[r], a[r + st]);
    float tmax = a[0];
    tmax = fmaxf(tmax, __shfl_xor(tmax, 32));

    // ---- defer-max rescale (T13; THR=11.5 in exp2 domain, 2^11.5 ~ 2896)
    if (__any(tmax > mrun + 11.5f)) {
      const float mnew = fmaxf(mrun, tmax);
      const float alpha = fast_exp2(mrun - mnew);  // exp2(-1e30)=0 on first tile
      mrun = mnew;
      lrun *= alpha;
      #pragma unroll
      for (int r = 0; r < 16; ++r) { y0[r] *= alpha; y1[r] *= alpha; }
    }

    // ---- P = exp2(S - m)  (bare v_exp_f32 — Q pre-scaled by log2e)
    #pragma unroll
    for (int r = 0; r < 16; ++r) {
      s0[r] = fast_exp2(s0[r] - mrun);
      s1[r] = fast_exp2(s1[r] - mrun);
    }

    // ---- column sum: tree + merge
    #pragma unroll
    for (int r = 0; r < 8; ++r) a[r] = s0[2 * r] + s0[2 * r + 1];
    #pragma unroll
    for (int r = 0; r < 8; ++r) a[8 + r] = s1[2 * r] + s1[2 * r + 1];
    #pragma unroll
    for (int st = 8; st > 0; st >>= 1)
      #pragma unroll
      for (int r = 0; r < 16; ++r) if (r < st) a[r] = a[r] + a[r + st];
    float rsum = a[0];
    rsum += __shfl_xor(rsum, 32);
    lrun += rsum;

    // ---- P^T B-fragments: cheap pack + permlane32_swap half-exchange.
    bf16x8 pf[4];
#if HAVE_PLSWAP
#define MK_PF(KS, SH, GA, HA)                                                 \
    {                                                                         \
      uint32_t g0 = pack_hu(SH[(GA)*4 + 0], SH[(GA)*4 + 1]);                  \
      uint32_t g1 = pack_hu(SH[(GA)*4 + 2], SH[(GA)*4 + 3]);                  \
      uint32_t h0 = pack_hu(SH[(HA)*4 + 0], SH[(HA)*4 + 1]);                  \
      uint32_t h1 = pack_hu(SH[(HA)*4 + 2], SH[(HA)*4 + 3]);                  \
      i32x2 r0 = __builtin_amdgcn_permlane32_swap((int)g0, (int)h0, false, false); \
      i32x2 r1 = __builtin_amdgcn_permlane32_swap((int)g1, (int)h1, false, false); \
      u32x4 t;                                                                \
      t[0] = (uint32_t)r0[0];                                                 \
      t[1] = (uint32_t)r1[0];                                                 \
      t[2] = (uint32_t)r0[1];                                                 \
      t[3] = (uint32_t)r1[1];                                                 \
      pf[KS] = __builtin_bit_cast(bf16x8, t);                                 \
    }
#else
#define MK_PF(KS, SH, GA, HA)                                                 \
    {                                                                         \
      uint32_t g0 = pack_hu(SH[(GA)*4 + 0], SH[(GA)*4 + 1]);                  \
      uint32_t g1 = pack_hu(SH[(GA)*4 + 2], SH[(GA)*4 + 3]);                  \
      uint32_t h0 = pack_hu(SH[(HA)*4 + 0], SH[(HA)*4 + 1]);                  \
      uint32_t h1 = pack_hu(SH[(HA)*4 + 2], SH[(HA)*4 + 3]);                  \
      uint32_t sg0 = (uint32_t)__shfl_xor((int)g0, 32);                       \
      uint32_t sg1 = (uint32_t)__shfl_xor((int)g1, 32);                       \
      uint32_t sh0 = (uint32_t)__shfl_xor((int)h0, 32);                       \
      uint32_t sh1 = (uint32_t)__shfl_xor((int)h1, 32);                       \
      u32x4 t;                                                                \
      t[0] = hi ? sh0 : g0;                                                   \
      t[1] = hi ? sh1 : g1;                                                   \
      t[2] = hi ? h0 : sg0;                                                   \
      t[3] = hi ? h1 : sg1;                                                   \
      pf[KS] = __builtin_bit_cast(bf16x8, t);                                 \
    }
#endif
    MK_PF(0, s0, 0, 1)
    MK_PF(1, s0, 2, 3)
    MK_PF(2, s1, 0, 1)
    MK_PF(3, s1, 2, 3)
#undef MK_PF

    // ---- PV: Y^T += V^T * P^T  (A = V^T frag rows d / d+32, B = pf)
    #pragma unroll
    for (int ks = 0; ks < 4; ++ks)
      y0 = __builtin_amdgcn_mfma_f32_32x32x16_bf16(vfA[ks], pf[ks], y0, 0, 0, 0);
    #pragma unroll
    for (int ks = 0; ks < 4; ++ks)
      y1 = __builtin_amdgcn_mfma_f32_32x32x16_bf16(vfB[ks], pf[ks], y1, 0, 0, 0);
  };

  // my tiles: wv, wv+4, wv+8, ...
  int it = wv;
  if (it < nt) {
    #pragma unroll
    for (int s = 0; s < 8; ++s)
      kfA[s] = *reinterpret_cast<const bf16x8*>(
          Kh + (wv << 12) + (s >> 2) * 2048 + (s & 3) * 512);
    for (;;) {
      tile_step(kfA, kfB, it);
      it += 4; if (it >= nt) break;
      tile_step(kfB, kfA, it);
      it += 4; if (it >= nt) break;
    }
  }

  // ---- cross-wave merge: waves 1-3 publish, wave0 combines + stores
  if (wv > 0) {
    Ml[wv - 1][lane] = mrun;
    Ll[wv - 1][lane] = lrun;
    #pragma unroll
    for (int r = 0; r < 16; ++r) {
      Yl[wv - 1][r][lane] = y0[r];
      Yl[wv - 1][16 + r][lane] = y1[r];
    }
  }
  __syncthreads();
  if (wv == 0) {
    float mp[3], lp[3];
    float mm = mrun;
    #pragma unroll
    for (int p = 0; p < 3; ++p) { mp[p] = Ml[p][lane]; mm = fmaxf(mm, mp[p]); }
    const float aw = fast_exp2(mrun - mm);
    float ap[3];
    float ll = lrun * aw;
    #pragma unroll
    for (int p = 0; p < 3; ++p) {
      ap[p] = fast_exp2(mp[p] - mm);        // 0 for empty partials (m=-1e30)
      ll += Ll[p][lane] * ap[p];
    }
    const float inv = 1.f / ll;

    const size_t ro = ((size_t)bb * T_ + qg) * C_ + hh * D_;
    #pragma unroll
    for (int q2 = 0; q2 < 4; ++q2) {
      float v[8];
      #pragma unroll
      for (int e = 0; e < 4; ++e) {
        float t0 = y0[q2 * 4 + e] * aw;
        float t1 = y1[q2 * 4 + e] * aw;
        #pragma unroll
        for (int p = 0; p < 3; ++p) {
          t0 += Yl[p][q2 * 4 + e][lane] * ap[p];
          t1 += Yl[p][16 + q2 * 4 + e][lane] * ap[p];
        }
        v[e] = t0 * inv;
        v[4 + e] = t1 * inv;
      }
      uint2 pr0 = {pack_hu(v[0], v[1]), pack_hu(v[2], v[3])};
      *reinterpret_cast<uint2*>(&Yb[ro + q2 * 8 + hi * 4]) = pr0;
      uint2 pr1 = {pack_hu(v[4], v[5]), pack_hu(v[6], v[7])};
      *reinterpret_cast<uint2*>(&Yb[ro + 32 + q2 * 8 + hi * 4]) = pr1;
    }
  }
}

// ---------------------------------------------------------------- launch
extern "C" void kernel_launch(void* const* d_in, const int* in_sizes, int n_in,
                              void* d_out, int out_size, void* d_ws, size_t ws_size,
                              hipStream_t stream) {
  const float* x      = (const float*)d_in[0];
  const float* w_attn = (const float*)d_in[1];
  const float* b_attn = (const float*)d_in[2];
  const float* w_proj = (const float*)d_in[3];
  const float* b_proj = (const float*)d_in[4];
  float* out = (float*)d_out;

  char* ws = (char*)d_ws;
  size_t off = 0;
  auto alloc = [&](size_t bytes) -> void* {
    void* p = ws + off;
    off += (bytes + 255) & ~(size_t)255;
    return p;
  };
  unsigned short* xb  = (unsigned short*)alloc((size_t)M_ * K_ * 2);       // x bf16
  unsigned short* waT = (unsigned short*)alloc((size_t)N1_ * K_ * 2);      // w_attn^T bf16
  unsigned short* wpT = (unsigned short*)alloc((size_t)C_ * K_ * 2);       // w_proj^T bf16
  unsigned short* Qb  = (unsigned short*)alloc((size_t)BH_ * T_ * D_ * 2); // [BH][T][D]
  unsigned short* Kb  = (unsigned short*)alloc((size_t)BH_ * T_ * D_ * 2); // tiled
  unsigned short* Vt  = (unsigned short*)alloc((size_t)BH_ * D_ * T_ * 2); // tiled
  unsigned short* Yb  = (unsigned short*)alloc((size_t)M_ * C_ * 2);       // attn out bf16

  cast_kernel<<<1024, 256, 0, stream>>>(x, xb, M_ * K_ / 4);
  transpose_cast<<<dim3(N1_ / 32, K_ / 32), dim3(32, 8), 0, stream>>>(w_attn, waT, K_, N1_);
  transpose_cast<<<dim3(C_ / 32, K_ / 32), dim3(32, 8), 0, stream>>>(w_proj, wpT, K_, C_);

  gemm_kernel<0><<<dim3(M_ / 128, N1_ / 128), 256, 0, stream>>>(
      xb, waT, b_attn, Qb, Kb, Vt, nullptr);

  attn_kernel<<<(T_ / 32) * BH_, 256, 0, stream>>>(Qb, Kb, Vt, Yb);

  gemm_kernel<1><<<dim3(M_ / 128, C_ / 128), 256, 0, stream>>>(
      Yb, wpT, b_proj, nullptr, nullptr, nullptr, out);
}

// Round 12
// 186.026 us; speedup vs baseline: 3.3745x; 3.3745x over previous
//
#include <hip/hip_runtime.h>
#include <stdint.h>

// Problem constants
#define B_   2
#define T_   4096
#define C_   768
#define H_   12
#define D_   64
#define BH_  24      // B_*H_
#define M_   8192    // B_*T_
#define K_   768
#define N1_  2304    // 3*C_

#define NEG_BIG (-1.0e30f)
// Q pre-scale: (1/sqrt(D)) * log2(e) -> attention runs in exp2 domain
#define QSCALE 0.18033688011112042f

typedef short bf16x8 __attribute__((ext_vector_type(8)));
typedef float f32x4  __attribute__((ext_vector_type(4)));
typedef float f32x16 __attribute__((ext_vector_type(16)));
typedef uint32_t u32x4 __attribute__((ext_vector_type(4)));
typedef int i32x2 __attribute__((ext_vector_type(2)));

typedef const __attribute__((address_space(1))) void* as1cv;
typedef __attribute__((address_space(3))) void*       as3v;

__device__ __forceinline__ void gload_lds16(const void* g, void* l) {
  __builtin_amdgcn_global_load_lds((as1cv)g, (as3v)l, 16, 0, 0);
}

// fp32 -> bf16 bits, round-to-nearest-even (input-fidelity paths).
// NOTE: v_cvt_pk_bf16_f32 inline-asm is POISONED on this toolchain (R2: NaN,
// R6: absmax 7.4e30). Software paths only.
__device__ __forceinline__ unsigned short f2bf(float f) {
  uint32_t x = __builtin_bit_cast(uint32_t, f);
  uint32_t r = (x + 0x7fffu + ((x >> 16) & 1u)) >> 16;
  return (unsigned short)r;
}

// cheap scalar pack: round-half-up, 2 VALU ops (<=0.5 ulp; 4x absmax headroom)
__device__ __forceinline__ unsigned short f2bf_hu(float f) {
  return (unsigned short)((__builtin_bit_cast(uint32_t, f) + 0x8000u) >> 16);
}

// cheap pair pack: round-half-up + byte-select (3 VALU via v_perm_b32)
#if __has_builtin(__builtin_amdgcn_perm)
__device__ __forceinline__ uint32_t pack_hu(float lo, float hi) {
  uint32_t a = __builtin_bit_cast(uint32_t, lo) + 0x8000u;
  uint32_t b = __builtin_bit_cast(uint32_t, hi) + 0x8000u;
  return __builtin_amdgcn_perm(b, a, 0x07060302u);
}
#else
__device__ __forceinline__ uint32_t pack_hu(float lo, float hi) {
  uint32_t a = __builtin_bit_cast(uint32_t, lo) + 0x8000u;
  uint32_t b = __builtin_bit_cast(uint32_t, hi) + 0x8000u;
  return (b & 0xFFFF0000u) | (a >> 16);
}
#endif

#if __has_builtin(__builtin_amdgcn_permlane32_swap)
#define HAVE_PLSWAP 1
#else
#define HAVE_PLSWAP 0
#endif

// native 2^x (v_exp_f32)
#if __has_builtin(__builtin_amdgcn_exp2f)
__device__ __forceinline__ float fast_exp2(float x) { return __builtin_amdgcn_exp2f(x); }
#else
__device__ __forceinline__ float fast_exp2(float x) { return __expf(x * 0.69314718056f); }
#endif

// ---------------------------------------------------------------- cast x -> bf16
__global__ void cast_kernel(const float* __restrict__ in, unsigned short* __restrict__ out, int n4) {
  int idx = blockIdx.x * blockDim.x + threadIdx.x;
  int stride = gridDim.x * blockDim.x;
  for (int i = idx; i < n4; i += stride) {
    float4 v = reinterpret_cast<const float4*>(in)[i];
    ushort4 o;
    o.x = f2bf(v.x); o.y = f2bf(v.y); o.z = f2bf(v.z); o.w = f2bf(v.w);
    reinterpret_cast<ushort4*>(out)[i] = o;
  }
}

// ------------------------------------------- transpose + cast: in[K][N] -> out[N][K] bf16
__global__ void transpose_cast(const float* __restrict__ in, unsigned short* __restrict__ out,
                               int K, int N) {
  __shared__ float tile[32][33];
  const int tx = threadIdx.x, ty = threadIdx.y;
  const int n = blockIdx.x * 32 + tx;
  #pragma unroll
  for (int r = 0; r < 4; ++r) {
    int k = blockIdx.y * 32 + ty + r * 8;
    tile[ty + r * 8][tx] = in[(size_t)k * N + n];
  }
  __syncthreads();
  const int k = blockIdx.y * 32 + tx;
  #pragma unroll
  for (int r = 0; r < 4; ++r) {
    int nn = blockIdx.x * 32 + ty + r * 8;
    out[(size_t)nn * K + k] = f2bf(tile[tx][ty + r * 8]);
  }
}

// ---------------------------------------------------------------- GEMM (m97-like)
// C[M][N] = A[M][768] * BT[N][768]^T + bias
// MODE 0: scatter epilogue -> Q [BH][T][D] (xQSCALE, exp2 domain), K & V^T in
//         MFMA-tiled layouts (attn fragment loads = base + lane*16B bursts).
// MODE 1: plain fp32 store to fo[M][768]
template <int MODE>
__global__ __launch_bounds__(256) void gemm_kernel(
    const unsigned short* __restrict__ A, const unsigned short* __restrict__ BT,
    const float* __restrict__ bias,
    unsigned short* __restrict__ o0, unsigned short* __restrict__ o1,
    unsigned short* __restrict__ o2, float* __restrict__ fo) {
  __shared__ __align__(16) unsigned short Al[128 * 32];
  __shared__ __align__(16) unsigned short Bl[128 * 32];
  const int tid = threadIdx.x;
  const int w = tid >> 6, lane = tid & 63;
  const int g = lane >> 4, c16 = lane & 15;
  const int wr = w >> 1, wc = w & 1;
  const int m0 = blockIdx.x * 128, n0 = blockIdx.y * 128;

  f32x4 acc[4][4] = {};

  for (int k0 = 0; k0 < K_; k0 += 32) {
    __syncthreads();
    #pragma unroll
    for (int q = 0; q < 2; ++q) {
      const int ch = (w * 2 + q) * 64 + lane;     // 0..511
      const int row = ch >> 2, kb = ch & 3;       // 128 rows x 4 x 16B
      gload_lds16(A  + (size_t)(m0 + row) * K_ + k0 + kb * 8, &Al[(w * 2 + q) * 512]);
      gload_lds16(BT + (size_t)(n0 + row) * K_ + k0 + kb * 8, &Bl[(w * 2 + q) * 512]);
    }
    __syncthreads();
    bf16x8 af[4], bfr[4];
    #pragma unroll
    for (int i = 0; i < 4; ++i) {
      af[i]  = *reinterpret_cast<const bf16x8*>(&Al[(wr * 64 + i * 16 + c16) * 32 + g * 8]);
      bfr[i] = *reinterpret_cast<const bf16x8*>(&Bl[(wc * 64 + i * 16 + c16) * 32 + g * 8]);
    }
    #pragma unroll
    for (int i = 0; i < 4; ++i)
      #pragma unroll
      for (int j = 0; j < 4; ++j)
        acc[i][j] = __builtin_amdgcn_mfma_f32_16x16x32_bf16(af[i], bfr[j], acc[i][j], 0, 0, 0);
  }

  const int which = (MODE == 0) ? (n0 / 768) : 0;
  #pragma unroll
  for (int i = 0; i < 4; ++i) {
    const int mbase = m0 + wr * 64 + i * 16 + g * 4;
    #pragma unroll
    for (int j2 = 0; j2 < 4; ++j2) {
      const int n = n0 + wc * 64 + j2 * 16 + c16;
      const float bv = bias[n];
      #pragma unroll
      for (int j = 0; j < 4; ++j) {
        float v = acc[i][j2][j] + bv;
        const int mm = mbase + j;
        if constexpr (MODE == 0) {
          const int cc = n - which * 768;
          const int hh = cc >> 6, dd = cc & 63;
          const int bb = mm >> 12, tt = mm & 4095;   // tt = kv/time index
          const size_t bh = (size_t)bb * H_ + hh;
          const size_t hb = bh * T_ * D_;
          if (which == 0) {
            o0[hb + (size_t)tt * D_ + dd] = f2bf_hu(v * QSCALE);  // Q, exp2 domain
          } else if (which == 1) {
            // K tiled: kv=tt, k=dd
            const int addr = ((tt >> 5) * 4 + (dd >> 4)) * 512 +
                             ((tt & 31) + ((dd >> 3) & 1) * 32) * 8 + (dd & 7);
            o1[hb + addr] = f2bf_hu(v);
          } else {
            // V^T tiled: d=dd, kv=tt
            const int addr = (tt >> 6) * 4096 + (dd >> 5) * 2048 +
                             ((tt >> 4) & 3) * 512 +
                             ((dd & 31) + ((tt >> 3) & 1) * 32) * 8 + (tt & 7);
            o2[hb + addr] = f2bf_hu(v);
          }
        } else {
          fo[(size_t)mm * 768 + n] = v;
        }
      }
    }
  }
}

// ---------------------------------------------------------------- flash attention
// 4 waves per block, SAME 32 q-rows, kv tiles split round-robin (wave w takes
// tiles it ≡ w mod 4) — quarters the serial causal tail (64 -> 16 tiles).
// Private online-softmax state per wave; waves 1-3 publish (m,l,y) via LDS
// once; wave0 merges lane-elementwise and stores.
// Tiled K/V layouts: every fragment load is base + lane*16B (coalesced burst).
// Depth-2 K register pipeline per wave. Swapped QK^T: lane owns ONE q-row.
// exp2 domain (Q pre-scaled by log2e/8): bare v_exp_f32, no muls.
// launch_bounds (256,2): R11's (256,4) clamped VGPR to 64 -> spilled y/kf to
// scratch (2.6 GB HBM traffic, 533 us). (256,2) keeps ~115 VGPR, no spill.
__global__ __launch_bounds__(256, 2) void attn_kernel(
    const unsigned short* __restrict__ Qb, const unsigned short* __restrict__ Kb,
    const unsigned short* __restrict__ Vt, unsigned short* __restrict__ Yb) {
  __shared__ float Ml[3][64];
  __shared__ float Ll[3][64];
  __shared__ __align__(16) float Yl[3][32][64];  // [partial][reg][lane] — conflict-free

  const int tidx = threadIdx.x;
  const int wv = tidx >> 6;       // 0..3: kv-split partner index
  const int lane = tidx & 63;
  const int q31 = lane & 31, hi = lane >> 5;
  const int bid = blockIdx.x;
  const int bh = bid % BH_;                     // bid%8 == bh%8 -> bh->XCD locality
  const int strip = (T_ / 32 - 1) - bid / BH_;  // 127..0, longest first
  const int q0 = strip * 32;
  const int qg = q0 + q31;  // this lane's q row

  const int bb = bh / H_, hh = bh % H_;
  const size_t hoff = (size_t)bh * T_ * D_;
  const unsigned short* Qh = Qb + hoff;
  const unsigned short* Kh = Kb + hoff + lane * 8;  // tiled: all frag loads + lane*8
  const unsigned short* Vh = Vt + hoff + lane * 8;

  // Q fragments: B-operand, col = q31, k = s*16 + hi*8 + e (one-time gather)
  bf16x8 qf[4];
  #pragma unroll
  for (int s = 0; s < 4; ++s)
    qf[s] = *reinterpret_cast<const bf16x8*>(&Qh[(size_t)qg * D_ + s * 16 + hi * 8]);

  float mrun = NEG_BIG, lrun = 0.f;
  f32x16 y0 = {}, y1 = {};

  const int nt = ((q0 + 31) >> 6) + 1;  // kv tiles 0..floor((q0+31)/64)

  // K fragment double buffer; tiled addr: it*4096 + (s>>2)*2048 + (s&3)*512
  bf16x8 kfA[8], kfB[8];

  auto tile_step = [&](bf16x8 (&kfc)[8], bf16x8 (&kfn)[8], int it) {
    const int kv0 = it << 6;

    // ---- V fragments for current tile (tiled: it*4096 + half*2048 + ks*512)
    const unsigned short* vB = Vh + it * 4096;
    bf16x8 vfA[4], vfB[4];
    #pragma unroll
    for (int ks = 0; ks < 4; ++ks) {
      vfA[ks] = *reinterpret_cast<const bf16x8*>(vB + ks * 512);
      vfB[ks] = *reinterpret_cast<const bf16x8*>(vB + 2048 + ks * 512);
    }

    // ---- K prefetch for MY next tile, it+4 (tail over-read stays in ws)
    const unsigned short* kN = Kh + it * 4096 + 16384;
    #pragma unroll
    for (int s = 0; s < 8; ++s)
      kfn[s] = *reinterpret_cast<const bf16x8*>(kN + (s >> 2) * 2048 + (s & 3) * 512);

    // ---- S^T = K * Q^T : two 32x32 half-tiles (kv 0..31, 32..63)
    f32x16 s0 = {}, s1 = {};
    #pragma unroll
    for (int s = 0; s < 4; ++s)
      s0 = __builtin_amdgcn_mfma_f32_32x32x16_bf16(kfc[s], qf[s], s0, 0, 0, 0);
    #pragma unroll
    for (int s = 0; s < 4; ++s)
      s1 = __builtin_amdgcn_mfma_f32_32x32x16_bf16(kfc[4 + s], qf[s], s1, 0, 0, 0);

    // ---- causal mask (finite sentinel); kv_local = (r&3)+8*(r>>2)+4*hi
    if (kv0 + 63 > q0) {
      #pragma unroll
      for (int r = 0; r < 16; ++r) {
        const int kvl = (r & 3) + 8 * (r >> 2) + 4 * hi;
        s0[r] = (kv0 + kvl > qg)      ? NEG_BIG : s0[r];
        s1[r] = (kv0 + 32 + kvl > qg) ? NEG_BIG : s1[r];
      }
    }

    // ---- column max: in-lane tree + cross-half merge (shfl_xor 32)
    float a[16];
    #pragma unroll
    for (int r = 0; r < 8; ++r) a[r] = fmaxf(s0[2 * r], s0[2 * r + 1]);
    #pragma unroll
    for (int r = 0; r < 8; ++r) a[8 + r] = fmaxf(s1[2 * r], s1[2 * r + 1]);
    #pragma unroll
    for (int st = 8; st > 0; st >>= 1)
      #pragma unroll
      for (int r = 0; r < 16; ++r) if (r < st) a[r] = fmaxf(a[r], a[r + st]);
    float tmax = a[0];
    tmax = fmaxf(tmax, __shfl_xor(tmax, 32));

    // ---- defer-max rescale (T13; THR=11.5 in exp2 domain, 2^11.5 ~ 2896)
    if (__any(tmax > mrun + 11.5f)) {
      const float mnew = fmaxf(mrun, tmax);
      const float alpha = fast_exp2(mrun - mnew);  // exp2(-1e30)=0 on first tile
      mrun = mnew;
      lrun *= alpha;
      #pragma unroll
      for (int r = 0; r < 16; ++r) { y0[r] *= alpha; y1[r] *= alpha; }
    }

    // ---- P = exp2(S - m)  (bare v_exp_f32 — Q pre-scaled by log2e)
    #pragma unroll
    for (int r = 0; r < 16; ++r) {
      s0[r] = fast_exp2(s0[r] - mrun);
      s1[r] = fast_exp2(s1[r] - mrun);
    }

    // ---- column sum: tree + merge
    #pragma unroll
    for (int r = 0; r < 8; ++r) a[r] = s0[2 * r] + s0[2 * r + 1];
    #pragma unroll
    for (int r = 0; r < 8; ++r) a[8 + r] = s1[2 * r] + s1[2 * r + 1];
    #pragma unroll
    for (int st = 8; st > 0; st >>= 1)
      #pragma unroll
      for (int r = 0; r < 16; ++r) if (r < st) a[r] = a[r] + a[r + st];
    float rsum = a[0];
    rsum += __shfl_xor(rsum, 32);
    lrun += rsum;

    // ---- P^T B-fragments: cheap pack + permlane32_swap half-exchange.
    bf16x8 pf[4];
#if HAVE_PLSWAP
#define MK_PF(KS, SH, GA, HA)                                                 \
    {                                                                         \
      uint32_t g0 = pack_hu(SH[(GA)*4 + 0], SH[(GA)*4 + 1]);                  \
      uint32_t g1 = pack_hu(SH[(GA)*4 + 2], SH[(GA)*4 + 3]);                  \
      uint32_t h0 = pack_hu(SH[(HA)*4 + 0], SH[(HA)*4 + 1]);                  \
      uint32_t h1 = pack_hu(SH[(HA)*4 + 2], SH[(HA)*4 + 3]);                  \
      i32x2 r0 = __builtin_amdgcn_permlane32_swap((int)g0, (int)h0, false, false); \
      i32x2 r1 = __builtin_amdgcn_permlane32_swap((int)g1, (int)h1, false, false); \
      u32x4 t;                                                                \
      t[0] = (uint32_t)r0[0];                                                 \
      t[1] = (uint32_t)r1[0];                                                 \
      t[2] = (uint32_t)r0[1];                                                 \
      t[3] = (uint32_t)r1[1];                                                 \
      pf[KS] = __builtin_bit_cast(bf16x8, t);                                 \
    }
#else
#define MK_PF(KS, SH, GA, HA)                                                 \
    {                                                                         \
      uint32_t g0 = pack_hu(SH[(GA)*4 + 0], SH[(GA)*4 + 1]);                  \
      uint32_t g1 = pack_hu(SH[(GA)*4 + 2], SH[(GA)*4 + 3]);                  \
      uint32_t h0 = pack_hu(SH[(HA)*4 + 0], SH[(HA)*4 + 1]);                  \
      uint32_t h1 = pack_hu(SH[(HA)*4 + 2], SH[(HA)*4 + 3]);                  \
      uint32_t sg0 = (uint32_t)__shfl_xor((int)g0, 32);                       \
      uint32_t sg1 = (uint32_t)__shfl_xor((int)g1, 32);                       \
      uint32_t sh0 = (uint32_t)__shfl_xor((int)h0, 32);                       \
      uint32_t sh1 = (uint32_t)__shfl_xor((int)h1, 32);                       \
      u32x4 t;                                                                \
      t[0] = hi ? sh0 : g0;                                                   \
      t[1] = hi ? sh1 : g1;                                                   \
      t[2] = hi ? h0 : sg0;                                                   \
      t[3] = hi ? h1 : sg1;                                                   \
      pf[KS] = __builtin_bit_cast(bf16x8, t);                                 \
    }
#endif
    MK_PF(0, s0, 0, 1)
    MK_PF(1, s0, 2, 3)
    MK_PF(2, s1, 0, 1)
    MK_PF(3, s1, 2, 3)
#undef MK_PF

    // ---- PV: Y^T += V^T * P^T  (A = V^T frag rows d / d+32, B = pf)
    #pragma unroll
    for (int ks = 0; ks < 4; ++ks)
      y0 = __builtin_amdgcn_mfma_f32_32x32x16_bf16(vfA[ks], pf[ks], y0, 0, 0, 0);
    #pragma unroll
    for (int ks = 0; ks < 4; ++ks)
      y1 = __builtin_amdgcn_mfma_f32_32x32x16_bf16(vfB[ks], pf[ks], y1, 0, 0, 0);
  };

  // my tiles: wv, wv+4, wv+8, ...
  int it = wv;
  if (it < nt) {
    #pragma unroll
    for (int s = 0; s < 8; ++s)
      kfA[s] = *reinterpret_cast<const bf16x8*>(
          Kh + (wv << 12) + (s >> 2) * 2048 + (s & 3) * 512);
    for (;;) {
      tile_step(kfA, kfB, it);
      it += 4; if (it >= nt) break;
      tile_step(kfB, kfA, it);
      it += 4; if (it >= nt) break;
    }
  }

  // ---- cross-wave merge: waves 1-3 publish, wave0 combines + stores
  if (wv > 0) {
    Ml[wv - 1][lane] = mrun;
    Ll[wv - 1][lane] = lrun;
    #pragma unroll
    for (int r = 0; r < 16; ++r) {
      Yl[wv - 1][r][lane] = y0[r];
      Yl[wv - 1][16 + r][lane] = y1[r];
    }
  }
  __syncthreads();
  if (wv == 0) {
    float mp[3];
    float mm = mrun;
    #pragma unroll
    for (int p = 0; p < 3; ++p) { mp[p] = Ml[p][lane]; mm = fmaxf(mm, mp[p]); }
    const float aw = fast_exp2(mrun - mm);
    float ap[3];
    float ll = lrun * aw;
    #pragma unroll
    for (int p = 0; p < 3; ++p) {
      ap[p] = fast_exp2(mp[p] - mm);        // 0 for empty partials (m=-1e30)
      ll += Ll[p][lane] * ap[p];
    }
    const float inv = 1.f / ll;

    const size_t ro = ((size_t)bb * T_ + qg) * C_ + hh * D_;
    #pragma unroll
    for (int q2 = 0; q2 < 4; ++q2) {
      float v[8];
      #pragma unroll
      for (int e = 0; e < 4; ++e) {
        float t0 = y0[q2 * 4 + e] * aw;
        float t1 = y1[q2 * 4 + e] * aw;
        #pragma unroll
        for (int p = 0; p < 3; ++p) {
          t0 += Yl[p][q2 * 4 + e][lane] * ap[p];
          t1 += Yl[p][16 + q2 * 4 + e][lane] * ap[p];
        }
        v[e] = t0 * inv;
        v[4 + e] = t1 * inv;
      }
      uint2 pr0 = {pack_hu(v[0], v[1]), pack_hu(v[2], v[3])};
      *reinterpret_cast<uint2*>(&Yb[ro + q2 * 8 + hi * 4]) = pr0;
      uint2 pr1 = {pack_hu(v[4], v[5]), pack_hu(v[6], v[7])};
      *reinterpret_cast<uint2*>(&Yb[ro + 32 + q2 * 8 + hi * 4]) = pr1;
    }
  }
}

// ---------------------------------------------------------------- launch
extern "C" void kernel_launch(void* const* d_in, const int* in_sizes, int n_in,
                              void* d_out, int out_size, void* d_ws, size_t ws_size,
                              hipStream_t stream) {
  const float* x      = (const float*)d_in[0];
  const float* w_attn = (const float*)d_in[1];
  const float* b_attn = (const float*)d_in[2];
  const float* w_proj = (const float*)d_in[3];
  const float* b_proj = (const float*)d_in[4];
  float* out = (float*)d_out;

  char* ws = (char*)d_ws;
  size_t off = 0;
  auto alloc = [&](size_t bytes) -> void* {
    void* p = ws + off;
    off += (bytes + 255) & ~(size_t)255;
    return p;
  };
  unsigned short* xb  = (unsigned short*)alloc((size_t)M_ * K_ * 2);       // x bf16
  unsigned short* waT = (unsigned short*)alloc((size_t)N1_ * K_ * 2);      // w_attn^T bf16
  unsigned short* wpT = (unsigned short*)alloc((size_t)C_ * K_ * 2);       // w_proj^T bf16
  unsigned short* Qb  = (unsigned short*)alloc((size_t)BH_ * T_ * D_ * 2); // [BH][T][D]
  unsigned short* Kb  = (unsigned short*)alloc((size_t)BH_ * T_ * D_ * 2); // tiled
  unsigned short* Vt  = (unsigned short*)alloc((size_t)BH_ * D_ * T_ * 2); // tiled
  unsigned short* Yb  = (unsigned short*)alloc((size_t)M_ * C_ * 2);       // attn out bf16

  cast_kernel<<<1024, 256, 0, stream>>>(x, xb, M_ * K_ / 4);
  transpose_cast<<<dim3(N1_ / 32, K_ / 32), dim3(32, 8), 0, stream>>>(w_attn, waT, K_, N1_);
  transpose_cast<<<dim3(C_ / 32, K_ / 32), dim3(32, 8), 0, stream>>>(w_proj, wpT, K_, C_);

  gemm_kernel<0><<<dim3(M_ / 128, N1_ / 128), 256, 0, stream>>>(
      xb, waT, b_attn, Qb, Kb, Vt, nullptr);

  attn_kernel<<<(T_ / 32) * BH_, 256, 0, stream>>>(Qb, Kb, Vt, Yb);

  gemm_kernel<1><<<dim3(M_ / 128, C_ / 128), 256, 0, stream>>>(
      Yb, wpT, b_proj, nullptr, nullptr, nullptr, out);
}

// Round 13
// 174.773 us; speedup vs baseline: 3.5917x; 1.0644x over previous
//
#include <hip/hip_runtime.h>
#include <stdint.h>

// Problem constants
#define B_   2
#define T_   4096
#define C_   768
#define H_   12
#define D_   64
#define BH_  24      // B_*H_
#define M_   8192    // B_*T_
#define K_   768
#define N1_  2304    // 3*C_

#define NEG_BIG (-1.0e30f)
// Q pre-scale: (1/sqrt(D)) * log2(e) -> attention runs in exp2 domain
#define QSCALE 0.18033688011112042f

typedef short bf16x8 __attribute__((ext_vector_type(8)));
typedef float f32x4  __attribute__((ext_vector_type(4)));
typedef float f32x16 __attribute__((ext_vector_type(16)));
typedef uint32_t u32x4 __attribute__((ext_vector_type(4)));
typedef int i32x2 __attribute__((ext_vector_type(2)));

typedef const __attribute__((address_space(1))) void* as1cv;
typedef __attribute__((address_space(3))) void*       as3v;

__device__ __forceinline__ void gload_lds16(const void* g, void* l) {
  __builtin_amdgcn_global_load_lds((as1cv)g, (as3v)l, 16, 0, 0);
}

// fp32 -> bf16 bits, round-to-nearest-even (input-fidelity paths).
// NOTE: v_cvt_pk_bf16_f32 inline-asm is POISONED on this toolchain (R2: NaN,
// R6: absmax 7.4e30). Software paths only.
__device__ __forceinline__ unsigned short f2bf(float f) {
  uint32_t x = __builtin_bit_cast(uint32_t, f);
  uint32_t r = (x + 0x7fffu + ((x >> 16) & 1u)) >> 16;
  return (unsigned short)r;
}

// cheap scalar pack: round-half-up, 2 VALU ops (<=0.5 ulp; 4x absmax headroom)
__device__ __forceinline__ unsigned short f2bf_hu(float f) {
  return (unsigned short)((__builtin_bit_cast(uint32_t, f) + 0x8000u) >> 16);
}

// cheap pair pack: round-half-up + byte-select (3 VALU via v_perm_b32)
#if __has_builtin(__builtin_amdgcn_perm)
__device__ __forceinline__ uint32_t pack_hu(float lo, float hi) {
  uint32_t a = __builtin_bit_cast(uint32_t, lo) + 0x8000u;
  uint32_t b = __builtin_bit_cast(uint32_t, hi) + 0x8000u;
  return __builtin_amdgcn_perm(b, a, 0x07060302u);
}
#else
__device__ __forceinline__ uint32_t pack_hu(float lo, float hi) {
  uint32_t a = __builtin_bit_cast(uint32_t, lo) + 0x8000u;
  uint32_t b = __builtin_bit_cast(uint32_t, hi) + 0x8000u;
  return (b & 0xFFFF0000u) | (a >> 16);
}
#endif

#if __has_builtin(__builtin_amdgcn_permlane32_swap)
#define HAVE_PLSWAP 1
#else
#define HAVE_PLSWAP 0
#endif

// native 2^x (v_exp_f32)
#if __has_builtin(__builtin_amdgcn_exp2f)
__device__ __forceinline__ float fast_exp2(float x) { return __builtin_amdgcn_exp2f(x); }
#else
__device__ __forceinline__ float fast_exp2(float x) { return __expf(x * 0.69314718056f); }
#endif

// ---------------------------------------------------------------- cast x -> bf16
__global__ void cast_kernel(const float* __restrict__ in, unsigned short* __restrict__ out, int n4) {
  int idx = blockIdx.x * blockDim.x + threadIdx.x;
  int stride = gridDim.x * blockDim.x;
  for (int i = idx; i < n4; i += stride) {
    float4 v = reinterpret_cast<const float4*>(in)[i];
    ushort4 o;
    o.x = f2bf(v.x); o.y = f2bf(v.y); o.z = f2bf(v.z); o.w = f2bf(v.w);
    reinterpret_cast<ushort4*>(out)[i] = o;
  }
}

// ------------------------------------------- transpose + cast: in[K][N] -> out[N][K] bf16
__global__ void transpose_cast(const float* __restrict__ in, unsigned short* __restrict__ out,
                               int K, int N) {
  __shared__ float tile[32][33];
  const int tx = threadIdx.x, ty = threadIdx.y;
  const int n = blockIdx.x * 32 + tx;
  #pragma unroll
  for (int r = 0; r < 4; ++r) {
    int k = blockIdx.y * 32 + ty + r * 8;
    tile[ty + r * 8][tx] = in[(size_t)k * N + n];
  }
  __syncthreads();
  const int k = blockIdx.y * 32 + tx;
  #pragma unroll
  for (int r = 0; r < 4; ++r) {
    int nn = blockIdx.x * 32 + ty + r * 8;
    out[(size_t)nn * K + k] = f2bf(tile[tx][ty + r * 8]);
  }
}

// ---------------------------------------------------------------- GEMM (m97-like)
// C[M][N] = A[M][768] * BT[N][768]^T + bias
// MODE 0: scatter epilogue -> Q [BH][T][D] (xQSCALE, exp2 domain), K & V^T in
//         MFMA-tiled layouts (attn fragment loads = base + lane*16B bursts).
// MODE 1: plain fp32 store to fo[M][768]
template <int MODE>
__global__ __launch_bounds__(256) void gemm_kernel(
    const unsigned short* __restrict__ A, const unsigned short* __restrict__ BT,
    const float* __restrict__ bias,
    unsigned short* __restrict__ o0, unsigned short* __restrict__ o1,
    unsigned short* __restrict__ o2, float* __restrict__ fo) {
  __shared__ __align__(16) unsigned short Al[128 * 32];
  __shared__ __align__(16) unsigned short Bl[128 * 32];
  const int tid = threadIdx.x;
  const int w = tid >> 6, lane = tid & 63;
  const int g = lane >> 4, c16 = lane & 15;
  const int wr = w >> 1, wc = w & 1;
  const int m0 = blockIdx.x * 128, n0 = blockIdx.y * 128;

  f32x4 acc[4][4] = {};

  for (int k0 = 0; k0 < K_; k0 += 32) {
    __syncthreads();
    #pragma unroll
    for (int q = 0; q < 2; ++q) {
      const int ch = (w * 2 + q) * 64 + lane;     // 0..511
      const int row = ch >> 2, kb = ch & 3;       // 128 rows x 4 x 16B
      gload_lds16(A  + (size_t)(m0 + row) * K_ + k0 + kb * 8, &Al[(w * 2 + q) * 512]);
      gload_lds16(BT + (size_t)(n0 + row) * K_ + k0 + kb * 8, &Bl[(w * 2 + q) * 512]);
    }
    __syncthreads();
    bf16x8 af[4], bfr[4];
    #pragma unroll
    for (int i = 0; i < 4; ++i) {
      af[i]  = *reinterpret_cast<const bf16x8*>(&Al[(wr * 64 + i * 16 + c16) * 32 + g * 8]);
      bfr[i] = *reinterpret_cast<const bf16x8*>(&Bl[(wc * 64 + i * 16 + c16) * 32 + g * 8]);
    }
    #pragma unroll
    for (int i = 0; i < 4; ++i)
      #pragma unroll
      for (int j = 0; j < 4; ++j)
        acc[i][j] = __builtin_amdgcn_mfma_f32_16x16x32_bf16(af[i], bfr[j], acc[i][j], 0, 0, 0);
  }

  const int which = (MODE == 0) ? (n0 / 768) : 0;
  #pragma unroll
  for (int i = 0; i < 4; ++i) {
    const int mbase = m0 + wr * 64 + i * 16 + g * 4;
    #pragma unroll
    for (int j2 = 0; j2 < 4; ++j2) {
      const int n = n0 + wc * 64 + j2 * 16 + c16;
      const float bv = bias[n];
      #pragma unroll
      for (int j = 0; j < 4; ++j) {
        float v = acc[i][j2][j] + bv;
        const int mm = mbase + j;
        if constexpr (MODE == 0) {
          const int cc = n - which * 768;
          const int hh = cc >> 6, dd = cc & 63;
          const int bb = mm >> 12, tt = mm & 4095;   // tt = kv/time index
          const size_t bh = (size_t)bb * H_ + hh;
          const size_t hb = bh * T_ * D_;
          if (which == 0) {
            o0[hb + (size_t)tt * D_ + dd] = f2bf_hu(v * QSCALE);  // Q, exp2 domain
          } else if (which == 1) {
            // K tiled: kv=tt, k=dd
            const int addr = ((tt >> 5) * 4 + (dd >> 4)) * 512 +
                             ((tt & 31) + ((dd >> 3) & 1) * 32) * 8 + (dd & 7);
            o1[hb + addr] = f2bf_hu(v);
          } else {
            // V^T tiled: d=dd, kv=tt
            const int addr = (tt >> 6) * 4096 + (dd >> 5) * 2048 +
                             ((tt >> 4) & 3) * 512 +
                             ((dd & 31) + ((tt >> 3) & 1) * 32) * 8 + (tt & 7);
            o2[hb + addr] = f2bf_hu(v);
          }
        } else {
          fo[(size_t)mm * 768 + n] = v;
        }
      }
    }
  }
}

// ---------------------------------------------------------------- flash attention
// 4 waves per block; each wave handles 64 q-rows (TWO 32-row S-tiles, A and B)
// against each K/V tile — the same 16 loads feed 32 MFMAs, halving L1/L2
// traffic per unit work (R12 showed a shared load-path throughput plateau).
// kv tiles split round-robin across waves (it ≡ wv mod 4); private softmax
// state per wave; waves 1-3 publish (m,l,y) via LDS; wave0 merges + stores.
// Tiled K/V layouts: every fragment load is base + lane*16B (coalesced burst).
// Swapped QK^T: lane owns ONE q-row per S-tile. exp2 domain, defer-max.
// launch_bounds (256,2): peak live state ~215 VGPR; (256,4) would spill (R11).
__global__ __launch_bounds__(256, 2) void attn_kernel(
    const unsigned short* __restrict__ Qb, const unsigned short* __restrict__ Kb,
    const unsigned short* __restrict__ Vt, unsigned short* __restrict__ Yb) {
  __shared__ float Ml[3][2][64];
  __shared__ float Ll[3][2][64];
  __shared__ __align__(16) float Yl[3][64][64];  // [partial][reg][lane] — conflict-free

  const int tidx = threadIdx.x;
  const int wv = tidx >> 6;       // 0..3: kv-split partner index
  const int lane = tidx & 63;
  const int q31 = lane & 31, hi = lane >> 5;
  const int bid = blockIdx.x;
  const int bh = bid % BH_;                     // bid%8 == bh%8 -> bh->XCD locality
  const int strip = (T_ / 64 - 1) - bid / BH_;  // 63..0, longest first
  const int q0 = strip * 64;
  const int qgA = q0 + q31;        // lane's q row, S-tile A
  const int qgB = q0 + 32 + q31;   // lane's q row, S-tile B

  const int bb = bh / H_, hh = bh % H_;
  const size_t hoff = (size_t)bh * T_ * D_;
  const unsigned short* Qh = Qb + hoff;
  const unsigned short* Kh = Kb + hoff + lane * 8;  // tiled: all frag loads + lane*8
  const unsigned short* Vh = Vt + hoff + lane * 8;

  // Q fragments for both S-tiles: B-operand, col = q31, k = s*16 + hi*8 + e
  bf16x8 qfA[4], qfB[4];
  #pragma unroll
  for (int s = 0; s < 4; ++s) {
    qfA[s] = *reinterpret_cast<const bf16x8*>(&Qh[(size_t)qgA * D_ + s * 16 + hi * 8]);
    qfB[s] = *reinterpret_cast<const bf16x8*>(&Qh[(size_t)qgB * D_ + s * 16 + hi * 8]);
  }

  float mA = NEG_BIG, lA = 0.f, mB = NEG_BIG, lB = 0.f;
  f32x16 yA0 = {}, yA1 = {}, yB0 = {}, yB1 = {};

  const int nt = strip + 1;  // kv tiles 0..strip

  for (int it = wv; it < nt; it += 4) {
    const int kv0 = it << 6;

    // ---- K fragments (tiled: it*4096 + (s>>2)*2048 + (s&3)*512)
    const unsigned short* kT = Kh + it * 4096;
    bf16x8 kf[8];
    #pragma unroll
    for (int s = 0; s < 8; ++s)
      kf[s] = *reinterpret_cast<const bf16x8*>(kT + (s >> 2) * 2048 + (s & 3) * 512);

    // ---- V fragments (tiled: it*4096 + half*2048 + ks*512); shared by A and B
    const unsigned short* vT = Vh + it * 4096;
    bf16x8 vlo[4], vhi[4];
    #pragma unroll
    for (int ks = 0; ks < 4; ++ks) {
      vlo[ks] = *reinterpret_cast<const bf16x8*>(vT + ks * 512);
      vhi[ks] = *reinterpret_cast<const bf16x8*>(vT + 2048 + ks * 512);
    }

    // ---- S^T = K * Q^T for both S-tiles (kv halves 0..31 / 32..63)
    f32x16 sA0 = {}, sA1 = {}, sB0 = {}, sB1 = {};
    #pragma unroll
    for (int s = 0; s < 4; ++s) {
      sA0 = __builtin_amdgcn_mfma_f32_32x32x16_bf16(kf[s], qfA[s], sA0, 0, 0, 0);
      sB0 = __builtin_amdgcn_mfma_f32_32x32x16_bf16(kf[s], qfB[s], sB0, 0, 0, 0);
    }
    #pragma unroll
    for (int s = 0; s < 4; ++s) {
      sA1 = __builtin_amdgcn_mfma_f32_32x32x16_bf16(kf[4 + s], qfA[s], sA1, 0, 0, 0);
      sB1 = __builtin_amdgcn_mfma_f32_32x32x16_bf16(kf[4 + s], qfB[s], sB1, 0, 0, 0);
    }

    // ---- causal mask: only the diagonal tile (it == strip, wave-uniform).
    // There: sA0 masked vs qgA, sA1 fully masked, sB0 untouched (kv<qgB always),
    // sB1 masked vs qgB. kv_local = (r&3)+8*(r>>2)+4*hi.
    if (it == strip) {
      #pragma unroll
      for (int r = 0; r < 16; ++r) {
        const int kvl = (r & 3) + 8 * (r >> 2) + 4 * hi;
        sA0[r] = (kv0 + kvl > qgA)      ? NEG_BIG : sA0[r];
        sA1[r] = NEG_BIG;
        sB1[r] = (kv0 + 32 + kvl > qgB) ? NEG_BIG : sB1[r];
      }
    }

    // ======== softmax + PV, S-tile A ========
    {
      float a[16];
      #pragma unroll
      for (int r = 0; r < 8; ++r) a[r] = fmaxf(sA0[2 * r], sA0[2 * r + 1]);
      #pragma unroll
      for (int r = 0; r < 8; ++r) a[8 + r] = fmaxf(sA1[2 * r], sA1[2 * r + 1]);
      #pragma unroll
      for (int st = 8; st > 0; st >>= 1)
        #pragma unroll
        for (int r = 0; r < 16; ++r) if (r < st) a[r] = fmaxf(a[r], a[r + st]);
      float tmax = a[0];
      tmax = fmaxf(tmax, __shfl_xor(tmax, 32));

      if (__any(tmax > mA + 11.5f)) {
        const float mnew = fmaxf(mA, tmax);
        const float alpha = fast_exp2(mA - mnew);
        mA = mnew;
        lA *= alpha;
        #pragma unroll
        for (int r = 0; r < 16; ++r) { yA0[r] *= alpha; yA1[r] *= alpha; }
      }
      #pragma unroll
      for (int r = 0; r < 16; ++r) {
        sA0[r] = fast_exp2(sA0[r] - mA);
        sA1[r] = fast_exp2(sA1[r] - mA);
      }
      #pragma unroll
      for (int r = 0; r < 8; ++r) a[r] = sA0[2 * r] + sA0[2 * r + 1];
      #pragma unroll
      for (int r = 0; r < 8; ++r) a[8 + r] = sA1[2 * r] + sA1[2 * r + 1];
      #pragma unroll
      for (int st = 8; st > 0; st >>= 1)
        #pragma unroll
        for (int r = 0; r < 16; ++r) if (r < st) a[r] = a[r] + a[r + st];
      float rsum = a[0];
      rsum += __shfl_xor(rsum, 32);
      lA += rsum;

      bf16x8 pf[4];
#if HAVE_PLSWAP
#define MK_PF(KS, SH, GA, HA)                                                 \
      {                                                                       \
        uint32_t g0 = pack_hu(SH[(GA)*4 + 0], SH[(GA)*4 + 1]);                \
        uint32_t g1 = pack_hu(SH[(GA)*4 + 2], SH[(GA)*4 + 3]);                \
        uint32_t h0 = pack_hu(SH[(HA)*4 + 0], SH[(HA)*4 + 1]);                \
        uint32_t h1 = pack_hu(SH[(HA)*4 + 2], SH[(HA)*4 + 3]);                \
        i32x2 r0 = __builtin_amdgcn_permlane32_swap((int)g0, (int)h0, false, false); \
        i32x2 r1 = __builtin_amdgcn_permlane32_swap((int)g1, (int)h1, false, false); \
        u32x4 t;                                                              \
        t[0] = (uint32_t)r0[0];                                               \
        t[1] = (uint32_t)r1[0];                                               \
        t[2] = (uint32_t)r0[1];                                               \
        t[3] = (uint32_t)r1[1];                                               \
        pf[KS] = __builtin_bit_cast(bf16x8, t);                               \
      }
#else
#define MK_PF(KS, SH, GA, HA)                                                 \
      {                                                                       \
        uint32_t g0 = pack_hu(SH[(GA)*4 + 0], SH[(GA)*4 + 1]);                \
        uint32_t g1 = pack_hu(SH[(GA)*4 + 2], SH[(GA)*4 + 3]);                \
        uint32_t h0 = pack_hu(SH[(HA)*4 + 0], SH[(HA)*4 + 1]);                \
        uint32_t h1 = pack_hu(SH[(HA)*4 + 2], SH[(HA)*4 + 3]);                \
        uint32_t sg0 = (uint32_t)__shfl_xor((int)g0, 32);                     \
        uint32_t sg1 = (uint32_t)__shfl_xor((int)g1, 32);                     \
        uint32_t sh0 = (uint32_t)__shfl_xor((int)h0, 32);                     \
        uint32_t sh1 = (uint32_t)__shfl_xor((int)h1, 32);                     \
        u32x4 t;                                                              \
        t[0] = hi ? sh0 : g0;                                                 \
        t[1] = hi ? sh1 : g1;                                                 \
        t[2] = hi ? h0 : sg0;                                                 \
        t[3] = hi ? h1 : sg1;                                                 \
        pf[KS] = __builtin_bit_cast(bf16x8, t);                               \
      }
#endif
      MK_PF(0, sA0, 0, 1)
      MK_PF(1, sA0, 2, 3)
      MK_PF(2, sA1, 0, 1)
      MK_PF(3, sA1, 2, 3)

      #pragma unroll
      for (int ks = 0; ks < 4; ++ks)
        yA0 = __builtin_amdgcn_mfma_f32_32x32x16_bf16(vlo[ks], pf[ks], yA0, 0, 0, 0);
      #pragma unroll
      for (int ks = 0; ks < 4; ++ks)
        yA1 = __builtin_amdgcn_mfma_f32_32x32x16_bf16(vhi[ks], pf[ks], yA1, 0, 0, 0);
    }

    // ======== softmax + PV, S-tile B ========
    {
      float a[16];
      #pragma unroll
      for (int r = 0; r < 8; ++r) a[r] = fmaxf(sB0[2 * r], sB0[2 * r + 1]);
      #pragma unroll
      for (int r = 0; r < 8; ++r) a[8 + r] = fmaxf(sB1[2 * r], sB1[2 * r + 1]);
      #pragma unroll
      for (int st = 8; st > 0; st >>= 1)
        #pragma unroll
        for (int r = 0; r < 16; ++r) if (r < st) a[r] = fmaxf(a[r], a[r + st]);
      float tmax = a[0];
      tmax = fmaxf(tmax, __shfl_xor(tmax, 32));

      if (__any(tmax > mB + 11.5f)) {
        const float mnew = fmaxf(mB, tmax);
        const float alpha = fast_exp2(mB - mnew);
        mB = mnew;
        lB *= alpha;
        #pragma unroll
        for (int r = 0; r < 16; ++r) { yB0[r] *= alpha; yB1[r] *= alpha; }
      }
      #pragma unroll
      for (int r = 0; r < 16; ++r) {
        sB0[r] = fast_exp2(sB0[r] - mB);
        sB1[r] = fast_exp2(sB1[r] - mB);
      }
      #pragma unroll
      for (int r = 0; r < 8; ++r) a[r] = sB0[2 * r] + sB0[2 * r + 1];
      #pragma unroll
      for (int r = 0; r < 8; ++r) a[8 + r] = sB1[2 * r] + sB1[2 * r + 1];
      #pragma unroll
      for (int st = 8; st > 0; st >>= 1)
        #pragma unroll
        for (int r = 0; r < 16; ++r) if (r < st) a[r] = a[r] + a[r + st];
      float rsum = a[0];
      rsum += __shfl_xor(rsum, 32);
      lB += rsum;

      bf16x8 pf[4];
      MK_PF(0, sB0, 0, 1)
      MK_PF(1, sB0, 2, 3)
      MK_PF(2, sB1, 0, 1)
      MK_PF(3, sB1, 2, 3)
#undef MK_PF

      #pragma unroll
      for (int ks = 0; ks < 4; ++ks)
        yB0 = __builtin_amdgcn_mfma_f32_32x32x16_bf16(vlo[ks], pf[ks], yB0, 0, 0, 0);
      #pragma unroll
      for (int ks = 0; ks < 4; ++ks)
        yB1 = __builtin_amdgcn_mfma_f32_32x32x16_bf16(vhi[ks], pf[ks], yB1, 0, 0, 0);
    }
  }

  // ---- cross-wave merge: waves 1-3 publish, wave0 combines + stores
  if (wv > 0) {
    Ml[wv - 1][0][lane] = mA; Ml[wv - 1][1][lane] = mB;
    Ll[wv - 1][0][lane] = lA; Ll[wv - 1][1][lane] = lB;
    #pragma unroll
    for (int r = 0; r < 16; ++r) {
      Yl[wv - 1][r][lane]      = yA0[r];
      Yl[wv - 1][16 + r][lane] = yA1[r];
      Yl[wv - 1][32 + r][lane] = yB0[r];
      Yl[wv - 1][48 + r][lane] = yB1[r];
    }
  }
  __syncthreads();
  if (wv == 0) {
    // ---- S-tile A
    {
      float mm = mA;
      #pragma unroll
      for (int p = 0; p < 3; ++p) mm = fmaxf(mm, Ml[p][0][lane]);
      const float aw = fast_exp2(mA - mm);
      float ap[3];
      float ll = lA * aw;
      #pragma unroll
      for (int p = 0; p < 3; ++p) {
        ap[p] = fast_exp2(Ml[p][0][lane] - mm);   // 0 for empty partials
        ll += Ll[p][0][lane] * ap[p];
      }
      const float inv = 1.f / ll;
      const size_t ro = ((size_t)bb * T_ + qgA) * C_ + hh * D_;
      #pragma unroll
      for (int q2 = 0; q2 < 4; ++q2) {
        float v[8];
        #pragma unroll
        for (int e = 0; e < 4; ++e) {
          float t0 = yA0[q2 * 4 + e] * aw;
          float t1 = yA1[q2 * 4 + e] * aw;
          #pragma unroll
          for (int p = 0; p < 3; ++p) {
            t0 += Yl[p][q2 * 4 + e][lane] * ap[p];
            t1 += Yl[p][16 + q2 * 4 + e][lane] * ap[p];
          }
          v[e] = t0 * inv;
          v[4 + e] = t1 * inv;
        }
        uint2 pr0 = {pack_hu(v[0], v[1]), pack_hu(v[2], v[3])};
        *reinterpret_cast<uint2*>(&Yb[ro + q2 * 8 + hi * 4]) = pr0;
        uint2 pr1 = {pack_hu(v[4], v[5]), pack_hu(v[6], v[7])};
        *reinterpret_cast<uint2*>(&Yb[ro + 32 + q2 * 8 + hi * 4]) = pr1;
      }
    }
    // ---- S-tile B
    {
      float mm = mB;
      #pragma unroll
      for (int p = 0; p < 3; ++p) mm = fmaxf(mm, Ml[p][1][lane]);
      const float aw = fast_exp2(mB - mm);
      float ap[3];
      float ll = lB * aw;
      #pragma unroll
      for (int p = 0; p < 3; ++p) {
        ap[p] = fast_exp2(Ml[p][1][lane] - mm);
        ll += Ll[p][1][lane] * ap[p];
      }
      const float inv = 1.f / ll;
      const size_t ro = ((size_t)bb * T_ + qgB) * C_ + hh * D_;
      #pragma unroll
      for (int q2 = 0; q2 < 4; ++q2) {
        float v[8];
        #pragma unroll
        for (int e = 0; e < 4; ++e) {
          float t0 = yB0[q2 * 4 + e] * aw;
          float t1 = yB1[q2 * 4 + e] * aw;
          #pragma unroll
          for (int p = 0; p < 3; ++p) {
            t0 += Yl[p][32 + q2 * 4 + e][lane] * ap[p];
            t1 += Yl[p][48 + q2 * 4 + e][lane] * ap[p];
          }
          v[e] = t0 * inv;
          v[4 + e] = t1 * inv;
        }
        uint2 pr0 = {pack_hu(v[0], v[1]), pack_hu(v[2], v[3])};
        *reinterpret_cast<uint2*>(&Yb[ro + q2 * 8 + hi * 4]) = pr0;
        uint2 pr1 = {pack_hu(v[4], v[5]), pack_hu(v[6], v[7])};
        *reinterpret_cast<uint2*>(&Yb[ro + 32 + q2 * 8 + hi * 4]) = pr1;
      }
    }
  }
}

// ---------------------------------------------------------------- launch
extern "C" void kernel_launch(void* const* d_in, const int* in_sizes, int n_in,
                              void* d_out, int out_size, void* d_ws, size_t ws_size,
                              hipStream_t stream) {
  const float* x      = (const float*)d_in[0];
  const float* w_attn = (const float*)d_in[1];
  const float* b_attn = (const float*)d_in[2];
  const float* w_proj = (const float*)d_in[3];
  const float* b_proj = (const float*)d_in[4];
  float* out = (float*)d_out;

  char* ws = (char*)d_ws;
  size_t off = 0;
  auto alloc = [&](size_t bytes) -> void* {
    void* p = ws + off;
    off += (bytes + 255) & ~(size_t)255;
    return p;
  };
  unsigned short* xb  = (unsigned short*)alloc((size_t)M_ * K_ * 2);       // x bf16
  unsigned short* waT = (unsigned short*)alloc((size_t)N1_ * K_ * 2);      // w_attn^T bf16
  unsigned short* wpT = (unsigned short*)alloc((size_t)C_ * K_ * 2);       // w_proj^T bf16
  unsigned short* Qb  = (unsigned short*)alloc((size_t)BH_ * T_ * D_ * 2); // [BH][T][D]
  unsigned short* Kb  = (unsigned short*)alloc((size_t)BH_ * T_ * D_ * 2); // tiled
  unsigned short* Vt  = (unsigned short*)alloc((size_t)BH_ * D_ * T_ * 2); // tiled
  unsigned short* Yb  = (unsigned short*)alloc((size_t)M_ * C_ * 2);       // attn out bf16

  cast_kernel<<<1024, 256, 0, stream>>>(x, xb, M_ * K_ / 4);
  transpose_cast<<<dim3(N1_ / 32, K_ / 32), dim3(32, 8), 0, stream>>>(w_attn, waT, K_, N1_);
  transpose_cast<<<dim3(C_ / 32, K_ / 32), dim3(32, 8), 0, stream>>>(w_proj, wpT, K_, C_);

  gemm_kernel<0><<<dim3(M_ / 128, N1_ / 128), 256, 0, stream>>>(
      xb, waT, b_attn, Qb, Kb, Vt, nullptr);

  attn_kernel<<<(T_ / 64) * BH_, 256, 0, stream>>>(Qb, Kb, Vt, Yb);

  gemm_kernel<1><<<dim3(M_ / 128, C_ / 128), 256, 0, stream>>>(
      Yb, wpT, b_proj, nullptr, nullptr, nullptr, out);
}

// Round 14
// 166.668 us; speedup vs baseline: 3.7664x; 1.0486x over previous
//
#include <hip/hip_runtime.h>
#include <stdint.h>

// Problem constants
#define B_   2
#define T_   4096
#define C_   768
#define H_   12
#define D_   64
#define BH_  24      // B_*H_
#define M_   8192    // B_*T_
#define K_   768
#define N1_  2304    // 3*C_

#define NEG_BIG (-1.0e30f)
// Q pre-scale: (1/sqrt(D)) * log2(e) -> attention runs in exp2 domain
#define QSCALE 0.18033688011112042f

typedef short bf16x8 __attribute__((ext_vector_type(8)));
typedef float f32x4  __attribute__((ext_vector_type(4)));
typedef float f32x16 __attribute__((ext_vector_type(16)));
typedef uint32_t u32x4 __attribute__((ext_vector_type(4)));
typedef int i32x2 __attribute__((ext_vector_type(2)));

typedef const __attribute__((address_space(1))) void* as1cv;
typedef __attribute__((address_space(3))) void*       as3v;

__device__ __forceinline__ void gload_lds16(const void* g, void* l) {
  __builtin_amdgcn_global_load_lds((as1cv)g, (as3v)l, 16, 0, 0);
}

// fp32 -> bf16 bits, round-to-nearest-even (input-fidelity paths).
// NOTE: v_cvt_pk_bf16_f32 inline-asm is POISONED on this toolchain (R2: NaN,
// R6: absmax 7.4e30). Software paths only.
__device__ __forceinline__ unsigned short f2bf(float f) {
  uint32_t x = __builtin_bit_cast(uint32_t, f);
  uint32_t r = (x + 0x7fffu + ((x >> 16) & 1u)) >> 16;
  return (unsigned short)r;
}

// cheap scalar pack: round-half-up, 2 VALU ops (<=0.5 ulp; 4x absmax headroom)
__device__ __forceinline__ unsigned short f2bf_hu(float f) {
  return (unsigned short)((__builtin_bit_cast(uint32_t, f) + 0x8000u) >> 16);
}

// cheap pair pack: round-half-up + byte-select (3 VALU via v_perm_b32)
#if __has_builtin(__builtin_amdgcn_perm)
__device__ __forceinline__ uint32_t pack_hu(float lo, float hi) {
  uint32_t a = __builtin_bit_cast(uint32_t, lo) + 0x8000u;
  uint32_t b = __builtin_bit_cast(uint32_t, hi) + 0x8000u;
  return __builtin_amdgcn_perm(b, a, 0x07060302u);
}
#else
__device__ __forceinline__ uint32_t pack_hu(float lo, float hi) {
  uint32_t a = __builtin_bit_cast(uint32_t, lo) + 0x8000u;
  uint32_t b = __builtin_bit_cast(uint32_t, hi) + 0x8000u;
  return (b & 0xFFFF0000u) | (a >> 16);
}
#endif

// unpack one bf16 half of a packed pair to f32 (1-2 VALU)
__device__ __forceinline__ float bfu(uint32_t w, int hb) {
  return __builtin_bit_cast(float, hb ? (w & 0xFFFF0000u) : (w << 16));
}

#if __has_builtin(__builtin_amdgcn_permlane32_swap)
#define HAVE_PLSWAP 1
#else
#define HAVE_PLSWAP 0
#endif

// native 2^x (v_exp_f32)
#if __has_builtin(__builtin_amdgcn_exp2f)
__device__ __forceinline__ float fast_exp2(float x) { return __builtin_amdgcn_exp2f(x); }
#else
__device__ __forceinline__ float fast_exp2(float x) { return __expf(x * 0.69314718056f); }
#endif

// ---------------------------------------------------------------- cast x -> bf16
__global__ void cast_kernel(const float* __restrict__ in, unsigned short* __restrict__ out, int n4) {
  int idx = blockIdx.x * blockDim.x + threadIdx.x;
  int stride = gridDim.x * blockDim.x;
  for (int i = idx; i < n4; i += stride) {
    float4 v = reinterpret_cast<const float4*>(in)[i];
    ushort4 o;
    o.x = f2bf(v.x); o.y = f2bf(v.y); o.z = f2bf(v.z); o.w = f2bf(v.w);
    reinterpret_cast<ushort4*>(out)[i] = o;
  }
}

// -------------------- fused transpose+cast for BOTH weights (one launch)
// a: [768][2304] -> oa [2304][768];  b: [768][768] -> ob [768][768]
__global__ void transpose_cast2(const float* __restrict__ a, unsigned short* __restrict__ oa,
                                const float* __restrict__ b, unsigned short* __restrict__ ob) {
  __shared__ float tile[32][33];
  const int bx = blockIdx.x;
  const float* in; unsigned short* out; int N, cb;
  if (bx < 72) { in = a; out = oa; N = 2304; cb = bx; }
  else         { in = b; out = ob; N = 768;  cb = bx - 72; }
  const int tx = threadIdx.x, ty = threadIdx.y;
  const int n = cb * 32 + tx;
  #pragma unroll
  for (int r = 0; r < 4; ++r) {
    int k = blockIdx.y * 32 + ty + r * 8;
    tile[ty + r * 8][tx] = in[(size_t)k * N + n];
  }
  __syncthreads();
  const int k = blockIdx.y * 32 + tx;
  #pragma unroll
  for (int r = 0; r < 4; ++r) {
    int nn = cb * 32 + ty + r * 8;
    out[(size_t)nn * K_ + k] = f2bf(tile[tx][ty + r * 8]);
  }
}

// ---------------------------------------------------------------- GEMM (m97-like)
// C[M][N] = A[M][768] * BT[N][768]^T + bias
// MODE 0: scatter epilogue -> Q [BH][T][D] (xQSCALE, exp2 domain), K & V^T in
//         MFMA-tiled layouts (attn fragment loads = base + lane*16B bursts).
//         Address strength-reduced: addr = addr0(i,j2) + j*stride.
// MODE 1: plain fp32 store to fo[M][768]
template <int MODE>
__global__ __launch_bounds__(256) void gemm_kernel(
    const unsigned short* __restrict__ A, const unsigned short* __restrict__ BT,
    const float* __restrict__ bias,
    unsigned short* __restrict__ o0, unsigned short* __restrict__ o1,
    unsigned short* __restrict__ o2, float* __restrict__ fo) {
  __shared__ __align__(16) unsigned short Al[128 * 32];
  __shared__ __align__(16) unsigned short Bl[128 * 32];
  const int tid = threadIdx.x;
  const int w = tid >> 6, lane = tid & 63;
  const int g = lane >> 4, c16 = lane & 15;
  const int wr = w >> 1, wc = w & 1;
  const int m0 = blockIdx.x * 128, n0 = blockIdx.y * 128;

  f32x4 acc[4][4] = {};

  for (int k0 = 0; k0 < K_; k0 += 32) {
    __syncthreads();
    #pragma unroll
    for (int q = 0; q < 2; ++q) {
      const int ch = (w * 2 + q) * 64 + lane;     // 0..511
      const int row = ch >> 2, kb = ch & 3;       // 128 rows x 4 x 16B
      gload_lds16(A  + (size_t)(m0 + row) * K_ + k0 + kb * 8, &Al[(w * 2 + q) * 512]);
      gload_lds16(BT + (size_t)(n0 + row) * K_ + k0 + kb * 8, &Bl[(w * 2 + q) * 512]);
    }
    __syncthreads();
    bf16x8 af[4], bfr[4];
    #pragma unroll
    for (int i = 0; i < 4; ++i) {
      af[i]  = *reinterpret_cast<const bf16x8*>(&Al[(wr * 64 + i * 16 + c16) * 32 + g * 8]);
      bfr[i] = *reinterpret_cast<const bf16x8*>(&Bl[(wc * 64 + i * 16 + c16) * 32 + g * 8]);
    }
    #pragma unroll
    for (int i = 0; i < 4; ++i)
      #pragma unroll
      for (int j = 0; j < 4; ++j)
        acc[i][j] = __builtin_amdgcn_mfma_f32_16x16x32_bf16(af[i], bfr[j], acc[i][j], 0, 0, 0);
  }

  const int which = (MODE == 0) ? (n0 / 768) : 0;
  #pragma unroll
  for (int i = 0; i < 4; ++i) {
    const int mbase = m0 + wr * 64 + i * 16 + g * 4;
    const int bb2 = mbase >> 12, tb = mbase & 4095;  // tt = tb + j, quad-aligned
    #pragma unroll
    for (int j2 = 0; j2 < 4; ++j2) {
      const int n = n0 + wc * 64 + j2 * 16 + c16;
      const float bv = bias[n];
      if constexpr (MODE == 0) {
        const int cc = n - which * 768;
        const int hh2 = cc >> 6, dd = cc & 63;
        const size_t hb = ((size_t)bb2 * H_ + hh2) * T_ * D_;
        if (which == 0) {
          const int addr0 = tb * 64 + dd;
          #pragma unroll
          for (int j = 0; j < 4; ++j)
            o0[hb + addr0 + j * 64] = f2bf_hu((acc[i][j2][j] + bv) * QSCALE);
        } else if (which == 1) {
          // K tiled; within j: tt&31 = (tb&31)+j (no 32-crossing) -> +8/j
          const int addr0 = ((tb >> 5) * 4 + (dd >> 4)) * 512 +
                            ((tb & 31) + ((dd >> 3) & 1) * 32) * 8 + (dd & 7);
          #pragma unroll
          for (int j = 0; j < 4; ++j)
            o1[hb + addr0 + j * 8] = f2bf_hu(acc[i][j2][j] + bv);
        } else {
          // V^T tiled; within j: tt&7 = (tb&7)+j (no 8-crossing) -> +1/j
          const int addr0 = (tb >> 6) * 4096 + (dd >> 5) * 2048 +
                            ((tb >> 4) & 3) * 512 +
                            ((dd & 31) + ((tb >> 3) & 1) * 32) * 8 + (tb & 7);
          #pragma unroll
          for (int j = 0; j < 4; ++j)
            o2[hb + addr0 + j] = f2bf_hu(acc[i][j2][j] + bv);
        }
      } else {
        #pragma unroll
        for (int j = 0; j < 4; ++j)
          fo[(size_t)(mbase + j) * 768 + n] = acc[i][j2][j] + bv;
      }
    }
  }
}

// ---------------------------------------------------------------- flash attention
// 4 waves/block; each wave: 64 q-rows (two 32-row S-tiles A,B) per K/V tile.
// kv tiles round-robin (it ≡ wv mod 4); private softmax state; waves 1-3
// publish (m,l,y-bf16-packed) via LDS; wave0 merges + stores.
// K-prefetch rotation: next tile's kf loads issue right AFTER the QK MFMAs
// (kf's last use) — they fly during softmax+PV (~1800 cy). V loads at tile
// top (consumed post-softmax, latency hidden under QK).
// Yl packed bf16 pairs: LDS 52->28 KB (+1 block/CU); merge error ~0.006.
// launch_bounds (256,2): R11 spill lesson — never force 4/EU.
__global__ __launch_bounds__(256, 2) void attn_kernel(
    const unsigned short* __restrict__ Qb, const unsigned short* __restrict__ Kb,
    const unsigned short* __restrict__ Vt, unsigned short* __restrict__ Yb) {
  __shared__ float Ml[3][2][64];
  __shared__ float Ll[3][2][64];
  __shared__ uint32_t Ylp[3][32][64];  // [partial][reg-pair][lane], bf16x2

  const int tidx = threadIdx.x;
  const int wv = tidx >> 6;       // 0..3: kv-split partner index
  const int lane = tidx & 63;
  const int q31 = lane & 31, hi = lane >> 5;
  const int bid = blockIdx.x;
  const int bh = bid % BH_;                     // bid%8 == bh%8 -> bh->XCD locality
  const int strip = (T_ / 64 - 1) - bid / BH_;  // 63..0, longest first
  const int q0 = strip * 64;
  const int qgA = q0 + q31;        // lane's q row, S-tile A
  const int qgB = q0 + 32 + q31;   // lane's q row, S-tile B

  const int bb = bh / H_, hh = bh % H_;
  const size_t hoff = (size_t)bh * T_ * D_;
  const unsigned short* Qh = Qb + hoff;
  const unsigned short* Kh = Kb + hoff + lane * 8;  // tiled: all frag loads + lane*8
  const unsigned short* Vh = Vt + hoff + lane * 8;

  // Q fragments for both S-tiles: B-operand, col = q31, k = s*16 + hi*8 + e
  bf16x8 qfA[4], qfB[4];
  #pragma unroll
  for (int s = 0; s < 4; ++s) {
    qfA[s] = *reinterpret_cast<const bf16x8*>(&Qh[(size_t)qgA * D_ + s * 16 + hi * 8]);
    qfB[s] = *reinterpret_cast<const bf16x8*>(&Qh[(size_t)qgB * D_ + s * 16 + hi * 8]);
  }

  float mA = NEG_BIG, lA = 0.f, mB = NEG_BIG, lB = 0.f;
  f32x16 yA0 = {}, yA1 = {}, yB0 = {}, yB1 = {};

  const int nt = strip + 1;  // kv tiles 0..strip

  // prologue: K fragments for my first tile (tile wv always exists in buffer)
  bf16x8 kf[8];
  {
    const unsigned short* kT = Kh + wv * 4096;
    #pragma unroll
    for (int s = 0; s < 8; ++s)
      kf[s] = *reinterpret_cast<const bf16x8*>(kT + (s >> 2) * 2048 + (s & 3) * 512);
  }

  for (int it = wv; it < nt; it += 4) {
    const int kv0 = it << 6;

    // ---- V fragments (consumed after softmax; latency hidden under QK)
    const unsigned short* vT = Vh + it * 4096;
    bf16x8 vlo[4], vhi[4];
    #pragma unroll
    for (int ks = 0; ks < 4; ++ks) {
      vlo[ks] = *reinterpret_cast<const bf16x8*>(vT + ks * 512);
      vhi[ks] = *reinterpret_cast<const bf16x8*>(vT + 2048 + ks * 512);
    }

    // ---- S^T = K * Q^T for both S-tiles (kf resident from prefetch)
    f32x16 sA0 = {}, sA1 = {}, sB0 = {}, sB1 = {};
    #pragma unroll
    for (int s = 0; s < 4; ++s) {
      sA0 = __builtin_amdgcn_mfma_f32_32x32x16_bf16(kf[s], qfA[s], sA0, 0, 0, 0);
      sB0 = __builtin_amdgcn_mfma_f32_32x32x16_bf16(kf[s], qfB[s], sB0, 0, 0, 0);
    }
    #pragma unroll
    for (int s = 0; s < 4; ++s) {
      sA1 = __builtin_amdgcn_mfma_f32_32x32x16_bf16(kf[4 + s], qfA[s], sA1, 0, 0, 0);
      sB1 = __builtin_amdgcn_mfma_f32_32x32x16_bf16(kf[4 + s], qfB[s], sB1, 0, 0, 0);
    }

    // ---- K prefetch for MY next tile (in-place rotate after last kf use;
    //      flies during softmax+PV; tail over-read stays inside ws)
    {
      const unsigned short* kT = Kh + (it + 4) * 4096;
      #pragma unroll
      for (int s = 0; s < 8; ++s)
        kf[s] = *reinterpret_cast<const bf16x8*>(kT + (s >> 2) * 2048 + (s & 3) * 512);
    }

    // ---- causal mask: only the diagonal tile (it == strip, wave-uniform).
    if (it == strip) {
      #pragma unroll
      for (int r = 0; r < 16; ++r) {
        const int kvl = (r & 3) + 8 * (r >> 2) + 4 * hi;
        sA0[r] = (kv0 + kvl > qgA)      ? NEG_BIG : sA0[r];
        sA1[r] = NEG_BIG;
        sB1[r] = (kv0 + 32 + kvl > qgB) ? NEG_BIG : sB1[r];
      }
    }

    // ======== softmax + PV, S-tile A ========
    {
      float a[16];
      #pragma unroll
      for (int r = 0; r < 8; ++r) a[r] = fmaxf(sA0[2 * r], sA0[2 * r + 1]);
      #pragma unroll
      for (int r = 0; r < 8; ++r) a[8 + r] = fmaxf(sA1[2 * r], sA1[2 * r + 1]);
      #pragma unroll
      for (int st = 8; st > 0; st >>= 1)
        #pragma unroll
        for (int r = 0; r < 16; ++r) if (r < st) a[r] = fmaxf(a[r], a[r + st]);
      float tmax = a[0];
      tmax = fmaxf(tmax, __shfl_xor(tmax, 32));

      if (__any(tmax > mA + 11.5f)) {
        const float mnew = fmaxf(mA, tmax);
        const float alpha = fast_exp2(mA - mnew);
        mA = mnew;
        lA *= alpha;
        #pragma unroll
        for (int r = 0; r < 16; ++r) { yA0[r] *= alpha; yA1[r] *= alpha; }
      }
      #pragma unroll
      for (int r = 0; r < 16; ++r) {
        sA0[r] = fast_exp2(sA0[r] - mA);
        sA1[r] = fast_exp2(sA1[r] - mA);
      }
      #pragma unroll
      for (int r = 0; r < 8; ++r) a[r] = sA0[2 * r] + sA0[2 * r + 1];
      #pragma unroll
      for (int r = 0; r < 8; ++r) a[8 + r] = sA1[2 * r] + sA1[2 * r + 1];
      #pragma unroll
      for (int st = 8; st > 0; st >>= 1)
        #pragma unroll
        for (int r = 0; r < 16; ++r) if (r < st) a[r] = a[r] + a[r + st];
      float rsum = a[0];
      rsum += __shfl_xor(rsum, 32);
      lA += rsum;

      bf16x8 pf[4];
#if HAVE_PLSWAP
#define MK_PF(KS, SH, GA, HA)                                                 \
      {                                                                       \
        uint32_t g0 = pack_hu(SH[(GA)*4 + 0], SH[(GA)*4 + 1]);                \
        uint32_t g1 = pack_hu(SH[(GA)*4 + 2], SH[(GA)*4 + 3]);                \
        uint32_t h0 = pack_hu(SH[(HA)*4 + 0], SH[(HA)*4 + 1]);                \
        uint32_t h1 = pack_hu(SH[(HA)*4 + 2], SH[(HA)*4 + 3]);                \
        i32x2 r0 = __builtin_amdgcn_permlane32_swap((int)g0, (int)h0, false, false); \
        i32x2 r1 = __builtin_amdgcn_permlane32_swap((int)g1, (int)h1, false, false); \
        u32x4 t;                                                              \
        t[0] = (uint32_t)r0[0];                                               \
        t[1] = (uint32_t)r1[0];                                               \
        t[2] = (uint32_t)r0[1];                                               \
        t[3] = (uint32_t)r1[1];                                               \
        pf[KS] = __builtin_bit_cast(bf16x8, t);                               \
      }
#else
#define MK_PF(KS, SH, GA, HA)                                                 \
      {                                                                       \
        uint32_t g0 = pack_hu(SH[(GA)*4 + 0], SH[(GA)*4 + 1]);                \
        uint32_t g1 = pack_hu(SH[(GA)*4 + 2], SH[(GA)*4 + 3]);                \
        uint32_t h0 = pack_hu(SH[(HA)*4 + 0], SH[(HA)*4 + 1]);                \
        uint32_t h1 = pack_hu(SH[(HA)*4 + 2], SH[(HA)*4 + 3]);                \
        uint32_t sg0 = (uint32_t)__shfl_xor((int)g0, 32);                     \
        uint32_t sg1 = (uint32_t)__shfl_xor((int)g1, 32);                     \
        uint32_t sh0 = (uint32_t)__shfl_xor((int)h0, 32);                     \
        uint32_t sh1 = (uint32_t)__shfl_xor((int)h1, 32);                     \
        u32x4 t;                                                              \
        t[0] = hi ? sh0 : g0;                                                 \
        t[1] = hi ? sh1 : g1;                                                 \
        t[2] = hi ? h0 : sg0;                                                 \
        t[3] = hi ? h1 : sg1;                                                 \
        pf[KS] = __builtin_bit_cast(bf16x8, t);                               \
      }
#endif
      MK_PF(0, sA0, 0, 1)
      MK_PF(1, sA0, 2, 3)
      MK_PF(2, sA1, 0, 1)
      MK_PF(3, sA1, 2, 3)

      #pragma unroll
      for (int ks = 0; ks < 4; ++ks)
        yA0 = __builtin_amdgcn_mfma_f32_32x32x16_bf16(vlo[ks], pf[ks], yA0, 0, 0, 0);
      #pragma unroll
      for (int ks = 0; ks < 4; ++ks)
        yA1 = __builtin_amdgcn_mfma_f32_32x32x16_bf16(vhi[ks], pf[ks], yA1, 0, 0, 0);
    }

    // ======== softmax + PV, S-tile B ========
    {
      float a[16];
      #pragma unroll
      for (int r = 0; r < 8; ++r) a[r] = fmaxf(sB0[2 * r], sB0[2 * r + 1]);
      #pragma unroll
      for (int r = 0; r < 8; ++r) a[8 + r] = fmaxf(sB1[2 * r], sB1[2 * r + 1]);
      #pragma unroll
      for (int st = 8; st > 0; st >>= 1)
        #pragma unroll
        for (int r = 0; r < 16; ++r) if (r < st) a[r] = fmaxf(a[r], a[r + st]);
      float tmax = a[0];
      tmax = fmaxf(tmax, __shfl_xor(tmax, 32));

      if (__any(tmax > mB + 11.5f)) {
        const float mnew = fmaxf(mB, tmax);
        const float alpha = fast_exp2(mB - mnew);
        mB = mnew;
        lB *= alpha;
        #pragma unroll
        for (int r = 0; r < 16; ++r) { yB0[r] *= alpha; yB1[r] *= alpha; }
      }
      #pragma unroll
      for (int r = 0; r < 16; ++r) {
        sB0[r] = fast_exp2(sB0[r] - mB);
        sB1[r] = fast_exp2(sB1[r] - mB);
      }
      #pragma unroll
      for (int r = 0; r < 8; ++r) a[r] = sB0[2 * r] + sB0[2 * r + 1];
      #pragma unroll
      for (int r = 0; r < 8; ++r) a[8 + r] = sB1[2 * r] + sB1[2 * r + 1];
      #pragma unroll
      for (int st = 8; st > 0; st >>= 1)
        #pragma unroll
        for (int r = 0; r < 16; ++r) if (r < st) a[r] = a[r] + a[r + st];
      float rsum = a[0];
      rsum += __shfl_xor(rsum, 32);
      lB += rsum;

      bf16x8 pf[4];
      MK_PF(0, sB0, 0, 1)
      MK_PF(1, sB0, 2, 3)
      MK_PF(2, sB1, 0, 1)
      MK_PF(3, sB1, 2, 3)
#undef MK_PF

      #pragma unroll
      for (int ks = 0; ks < 4; ++ks)
        yB0 = __builtin_amdgcn_mfma_f32_32x32x16_bf16(vlo[ks], pf[ks], yB0, 0, 0, 0);
      #pragma unroll
      for (int ks = 0; ks < 4; ++ks)
        yB1 = __builtin_amdgcn_mfma_f32_32x32x16_bf16(vhi[ks], pf[ks], yB1, 0, 0, 0);
    }
  }

  // ---- cross-wave merge: waves 1-3 publish (bf16 pairs), wave0 combines
  if (wv > 0) {
    Ml[wv - 1][0][lane] = mA; Ml[wv - 1][1][lane] = mB;
    Ll[wv - 1][0][lane] = lA; Ll[wv - 1][1][lane] = lB;
    #pragma unroll
    for (int r = 0; r < 8; ++r) {
      Ylp[wv - 1][r][lane]      = pack_hu(yA0[2 * r], yA0[2 * r + 1]);
      Ylp[wv - 1][8 + r][lane]  = pack_hu(yA1[2 * r], yA1[2 * r + 1]);
      Ylp[wv - 1][16 + r][lane] = pack_hu(yB0[2 * r], yB0[2 * r + 1]);
      Ylp[wv - 1][24 + r][lane] = pack_hu(yB1[2 * r], yB1[2 * r + 1]);
    }
  }
  __syncthreads();
  if (wv == 0) {
    // ---- S-tile A
    {
      float mm = mA;
      #pragma unroll
      for (int p = 0; p < 3; ++p) mm = fmaxf(mm, Ml[p][0][lane]);
      const float aw = fast_exp2(mA - mm);
      float ap[3];
      float ll = lA * aw;
      #pragma unroll
      for (int p = 0; p < 3; ++p) {
        ap[p] = fast_exp2(Ml[p][0][lane] - mm);   // 0 for empty partials
        ll += Ll[p][0][lane] * ap[p];
      }
      const float inv = 1.f / ll;
      const size_t ro = ((size_t)bb * T_ + qgA) * C_ + hh * D_;
      #pragma unroll
      for (int q2 = 0; q2 < 4; ++q2) {
        float v[8];
        #pragma unroll
        for (int e = 0; e < 4; ++e) {
          const int pr = q2 * 2 + (e >> 1), hb2 = e & 1;
          float t0 = yA0[q2 * 4 + e] * aw;
          float t1 = yA1[q2 * 4 + e] * aw;
          #pragma unroll
          for (int p = 0; p < 3; ++p) {
            t0 += bfu(Ylp[p][pr][lane], hb2) * ap[p];
            t1 += bfu(Ylp[p][8 + pr][lane], hb2) * ap[p];
          }
          v[e] = t0 * inv;
          v[4 + e] = t1 * inv;
        }
        uint2 pr0 = {pack_hu(v[0], v[1]), pack_hu(v[2], v[3])};
        *reinterpret_cast<uint2*>(&Yb[ro + q2 * 8 + hi * 4]) = pr0;
        uint2 pr1 = {pack_hu(v[4], v[5]), pack_hu(v[6], v[7])};
        *reinterpret_cast<uint2*>(&Yb[ro + 32 + q2 * 8 + hi * 4]) = pr1;
      }
    }
    // ---- S-tile B
    {
      float mm = mB;
      #pragma unroll
      for (int p = 0; p < 3; ++p) mm = fmaxf(mm, Ml[p][1][lane]);
      const float aw = fast_exp2(mB - mm);
      float ap[3];
      float ll = lB * aw;
      #pragma unroll
      for (int p = 0; p < 3; ++p) {
        ap[p] = fast_exp2(Ml[p][1][lane] - mm);
        ll += Ll[p][1][lane] * ap[p];
      }
      const float inv = 1.f / ll;
      const size_t ro = ((size_t)bb * T_ + qgB) * C_ + hh * D_;
      #pragma unroll
      for (int q2 = 0; q2 < 4; ++q2) {
        float v[8];
        #pragma unroll
        for (int e = 0; e < 4; ++e) {
          const int pr = q2 * 2 + (e >> 1), hb2 = e & 1;
          float t0 = yB0[q2 * 4 + e] * aw;
          float t1 = yB1[q2 * 4 + e] * aw;
          #pragma unroll
          for (int p = 0; p < 3; ++p) {
            t0 += bfu(Ylp[p][16 + pr][lane], hb2) * ap[p];
            t1 += bfu(Ylp[p][24 + pr][lane], hb2) * ap[p];
          }
          v[e] = t0 * inv;
          v[4 + e] = t1 * inv;
        }
        uint2 pr0 = {pack_hu(v[0], v[1]), pack_hu(v[2], v[3])};
        *reinterpret_cast<uint2*>(&Yb[ro + q2 * 8 + hi * 4]) = pr0;
        uint2 pr1 = {pack_hu(v[4], v[5]), pack_hu(v[6], v[7])};
        *reinterpret_cast<uint2*>(&Yb[ro + 32 + q2 * 8 + hi * 4]) = pr1;
      }
    }
  }
}

// ---------------------------------------------------------------- launch
extern "C" void kernel_launch(void* const* d_in, const int* in_sizes, int n_in,
                              void* d_out, int out_size, void* d_ws, size_t ws_size,
                              hipStream_t stream) {
  const float* x      = (const float*)d_in[0];
  const float* w_attn = (const float*)d_in[1];
  const float* b_attn = (const float*)d_in[2];
  const float* w_proj = (const float*)d_in[3];
  const float* b_proj = (const float*)d_in[4];
  float* out = (float*)d_out;

  char* ws = (char*)d_ws;
  size_t off = 0;
  auto alloc = [&](size_t bytes) -> void* {
    void* p = ws + off;
    off += (bytes + 255) & ~(size_t)255;
    return p;
  };
  unsigned short* xb  = (unsigned short*)alloc((size_t)M_ * K_ * 2);       // x bf16
  unsigned short* waT = (unsigned short*)alloc((size_t)N1_ * K_ * 2);      // w_attn^T bf16
  unsigned short* wpT = (unsigned short*)alloc((size_t)C_ * K_ * 2);       // w_proj^T bf16
  unsigned short* Qb  = (unsigned short*)alloc((size_t)BH_ * T_ * D_ * 2); // [BH][T][D]
  unsigned short* Kb  = (unsigned short*)alloc((size_t)BH_ * T_ * D_ * 2); // tiled
  unsigned short* Vt  = (unsigned short*)alloc((size_t)BH_ * D_ * T_ * 2); // tiled
  unsigned short* Yb  = (unsigned short*)alloc((size_t)M_ * C_ * 2);       // attn out bf16

  cast_kernel<<<1024, 256, 0, stream>>>(x, xb, M_ * K_ / 4);
  transpose_cast2<<<dim3(96, 24), dim3(32, 8), 0, stream>>>(w_attn, waT, w_proj, wpT);

  gemm_kernel<0><<<dim3(M_ / 128, N1_ / 128), 256, 0, stream>>>(
      xb, waT, b_attn, Qb, Kb, Vt, nullptr);

  attn_kernel<<<(T_ / 64) * BH_, 256, 0, stream>>>(Qb, Kb, Vt, Yb);

  gemm_kernel<1><<<dim3(M_ / 128, C_ / 128), 256, 0, stream>>>(
      Yb, wpT, b_proj, nullptr, nullptr, nullptr, out);
}